// Round 8
// baseline (138.561 us; speedup 1.0000x reference)
//
#include <hip/hip_runtime.h>

#define BSZ 4096
#define D 1024
#define N2 8192
#define TEMPV 0.5f
// exp(x/T) = exp2(x * log2(e)/T)
#define EXPSCALE 2.8853900817779268f
#define NTB 32      // 8192 / 256 tiles per dim

typedef __attribute__((ext_vector_type(8))) short bf16x8;
typedef __attribute__((ext_vector_type(4))) float f32x4;

__device__ inline unsigned short f2bf(float x) {
  unsigned int u = __float_as_uint(x);
  u += 0x7fffu + ((u >> 16) & 1u);   // round-to-nearest-even
  return (unsigned short)(u >> 16);
}

__device__ inline void gload16(const void* g, void* l) {
  __builtin_amdgcn_global_load_lds(
      (const __attribute__((address_space(1))) void*)g,
      (__attribute__((address_space(3))) void*)l, 16, 0, 0);
}

// ---------------- Kernel A: L2-normalize rows, emit bf16 reps + pos dot ----------------
__global__ __launch_bounds__(256) void knorm(const float* __restrict__ ei,
                                             const float* __restrict__ ej,
                                             unsigned short* __restrict__ reps,
                                             float* __restrict__ pos) {
  const int r = blockIdx.x;
  const int t = threadIdx.x;
  const float4 vi = ((const float4*)(ei + (size_t)r * D))[t];
  const float4 vj = ((const float4*)(ej + (size_t)r * D))[t];
  float ssi = vi.x * vi.x + vi.y * vi.y + vi.z * vi.z + vi.w * vi.w;
  float ssj = vj.x * vj.x + vj.y * vj.y + vj.z * vj.z + vj.w * vj.w;
  float sij = vi.x * vj.x + vi.y * vj.y + vi.z * vj.z + vi.w * vj.w;
#pragma unroll
  for (int o = 32; o > 0; o >>= 1) {
    ssi += __shfl_xor(ssi, o);
    ssj += __shfl_xor(ssj, o);
    sij += __shfl_xor(sij, o);
  }
  __shared__ float red[12];
  const int lane = t & 63, wid = t >> 6;
  if (lane == 0) { red[wid * 3] = ssi; red[wid * 3 + 1] = ssj; red[wid * 3 + 2] = sij; }
  __syncthreads();
  ssi = red[0] + red[3] + red[6] + red[9];
  ssj = red[1] + red[4] + red[7] + red[10];
  sij = red[2] + red[5] + red[8] + red[11];
  const float inv_i = rsqrtf(fmaxf(ssi, 1e-24f));
  const float inv_j = rsqrtf(fmaxf(ssj, 1e-24f));
  ushort4 ui, uj;
  ui.x = f2bf(vi.x * inv_i); ui.y = f2bf(vi.y * inv_i);
  ui.z = f2bf(vi.z * inv_i); ui.w = f2bf(vi.w * inv_i);
  uj.x = f2bf(vj.x * inv_j); uj.y = f2bf(vj.y * inv_j);
  uj.z = f2bf(vj.z * inv_j); uj.w = f2bf(vj.w * inv_j);
  *((ushort4*)(reps + (size_t)r * D) + t) = ui;
  *((ushort4*)(reps + (size_t)(BSZ + r) * D) + t) = uj;
  if (t == 0) pos[r] = sij * inv_i * inv_j;
}

// ======================= shared asm helpers =======================
#define BARRIER() do { __builtin_amdgcn_s_barrier(); asm volatile("" ::: "memory"); } while (0)
#define STR2(x) #x
#define WAITV(n) asm volatile("s_waitcnt vmcnt(" STR2(n) ")" ::: "memory")
#define LGKM0() asm volatile("s_waitcnt lgkmcnt(0)" ::: "memory")

// ---------------- Kernel B: 256x256 tiles (512 = 2 clean rounds), B-direct engine -------
// 8 waves (2M x 4N), wave tile 128x64, BK=64. A staged in LDS (64 KiB dbuf);
// B fragments loaded DIRECT global->registers (L2-served) to relieve the LDS read pipe
// (was 24 ds_read_b128/wave/tile; now 16 + half the LDS writes).
// Ledger: ph1(t) stages A(t+1) (4 gload_lds/thread); ph3-end vmcnt(0) drains it
// (nothing else in flight there: B(t) regs retired by compiler waits during ph1,
// B(t+1) not yet issued) -> ph4 reads of A(t+1) safe after barrier. B(t+1) regs
// issue in ph4 after MFMA_Q3 (their last reader); covered by barrier + ph1 issue.
#define SG_A(ii, ktv, dst) gload16(reps + (arow0 + (ii) * 64 + srow8) * D + (ktv) * 64 + schunk * 8, \
                                   (dst) + (size_t)((ii) * 64 + w * 8) * 64)

#define READ_AQ(buf, q) do {                                            \
    const char* rp0_ = (buf) + (arow + (2 * (q)) * 16) * 128;           \
    const char* rp1_ = (buf) + (arow + (2 * (q) + 1) * 16) * 128;       \
    af[0][0] = *(const bf16x8*)(rp0_ + offk0);                          \
    af[0][1] = *(const bf16x8*)(rp0_ + offk1);                          \
    af[1][0] = *(const bf16x8*)(rp1_ + offk0);                          \
    af[1][1] = *(const bf16x8*)(rp1_ + offk1);                          \
  } while (0)

// B fragment straight from global: same register contents as the old LDS path
// (staging swizzle and read swizzle cancel; cols = ktv*64 + kk*32 + ((l>>4)&3)*8).
#define READ_B2G(ktv, n) do {                                           \
    bfr[n][0] = *(const bf16x8*)(bbase + (size_t)(n) * 16 * D + (ktv) * 64);      \
    bfr[n][1] = *(const bf16x8*)(bbase + (size_t)(n) * 16 * D + (ktv) * 64 + 32); \
  } while (0)

// 16 MFMA for one 32-row M-quadrant x all 64 N-cols.
#define MFMA_Q(q)                                                       \
  __builtin_amdgcn_s_setprio(1);                                        \
  _Pragma("unroll") for (int nh = 0; nh < 2; nh++)                      \
  _Pragma("unroll") for (int kk = 0; kk < 2; kk++)                      \
  _Pragma("unroll") for (int m2 = 0; m2 < 2; m2++)                      \
  _Pragma("unroll") for (int nn = 0; nn < 2; nn++) {                    \
    const int n_ = nh * 2 + nn;                                         \
    acc[2 * (q) + m2][n_] = __builtin_amdgcn_mfma_f32_16x16x32_bf16(    \
        af[m2][kk], bfr[n_][kk], acc[2 * (q) + m2][n_], 0, 0, 0);       \
  }                                                                     \
  __builtin_amdgcn_s_setprio(0);

#define DO_TILE(ktv, SA, RDN)                                           \
  {                                                                     \
    const int cur = (ktv) & 1;                                          \
    const char* bA  = cur ? (const char*)lA1 : (const char*)lA0;        \
    const char* bAn = cur ? (const char*)lA0 : (const char*)lA1;        \
    short* stA = cur ? lA0 : lA1;                                       \
    /* ph1: q0 MFMA (ops loaded in prev ph4); read Aq1; stage A(t+1) */ \
    MFMA_Q(0);                                                          \
    READ_AQ(bA, 1);                                                     \
    if (SA) { SG_A(0, (ktv) + 1, stA); SG_A(1, (ktv) + 1, stA);         \
              SG_A(2, (ktv) + 1, stA); SG_A(3, (ktv) + 1, stA); }       \
    BARRIER();                                                          \
    /* ph2 */                                                           \
    MFMA_Q(1);                                                          \
    READ_AQ(bA, 2);                                                     \
    BARRIER();                                                          \
    /* ph3: drain own A(t+1) stage before the visibility barrier */     \
    MFMA_Q(2);                                                          \
    READ_AQ(bA, 3);                                                     \
    WAITV(0);                                                           \
    BARRIER();                                                          \
    /* ph4: last quadrant; then next tile's Aq0 (LDS) + B frags (global) */ \
    MFMA_Q(3);                                                          \
    if (RDN) { READ_AQ(bAn, 0);                                         \
               READ_B2G((ktv) + 1, 0); READ_B2G((ktv) + 1, 1);          \
               READ_B2G((ktv) + 1, 2); READ_B2G((ktv) + 1, 3); }        \
    BARRIER();                                                          \
  }

__global__ __launch_bounds__(512, 2) void kgemm3(const short* __restrict__ reps,
                                                 float* __restrict__ partial) {
  extern __shared__ char smem[];
  short* lA0 = (short*)smem;                  // 32 KB  [256][64]
  short* lA1 = (short*)(smem + 32768);

  // XCD-aware swizzle (512 = 8 * 64, bijective), then decode into the
  // 512-tile list: triangle minus tiles (0, 16..31).
  int bid = (int)blockIdx.x;
  bid = (bid & 7) * 64 + (bid >> 3);
  int rb, cb;
  if (bid < 16) {
    rb = 0; cb = bid;
  } else {
    int rem = bid - 16;
    rb = 1;
    while (rem >= NTB - rb) { rem -= NTB - rb; rb++; }
    cb = rb + rem;
  }

  const int t = threadIdx.x;
  const int l = t & 63, w = t >> 6;
  const int wr = w >> 2, wc = w & 3;          // 2 x 4 wave grid

  f32x4 acc[8][4];
  const f32x4 zero4 = {0.f, 0.f, 0.f, 0.f};
#pragma unroll
  for (int m = 0; m < 8; m++)
#pragma unroll
    for (int n = 0; n < 4; n++) acc[m][n] = zero4;

  const int srow8 = w * 8 + (l >> 3);          // row within 64-row inst chunk
  const int schunk = (l & 7) ^ (l >> 3);       // pre-swizzled source 16B chunk
  const size_t arow0 = (size_t)rb * 256;
  const size_t brow0 = (size_t)cb * 256;

  const int swz = (l & 7) << 4;
  const int q16 = ((l >> 4) & 3) * 16;
  const int arow = wr * 128 + (l & 15);
  const int brow = wc * 64 + (l & 15);
  const int offk0 = (q16) ^ swz;
  const int offk1 = (64 + q16) ^ swz;

  // per-thread global base for B fragments
  const short* bbase = reps + (brow0 + brow) * D + ((l >> 4) & 3) * 8;

  // ---- prologue: stage A(0); load B(0) frags; full drain (one-time) ----
  SG_A(0, 0, lA0); SG_A(1, 0, lA0); SG_A(2, 0, lA0); SG_A(3, 0, lA0);
  bf16x8 af[2][2], bfr[4][2];
  READ_B2G(0, 0); READ_B2G(0, 1); READ_B2G(0, 2); READ_B2G(0, 3);
  WAITV(0);
  BARRIER();
  READ_AQ((const char*)lA0, 0);

#pragma unroll 1
  for (int kt = 0; kt < 15; ++kt) DO_TILE(kt, 1, 1)
  DO_TILE(15, 0, 0)

  // -------- epilogue: exp + diagonal mask + row/col partial sums --------
  float rsum[8][4];
  float csum[4];
#pragma unroll
  for (int m = 0; m < 8; m++)
#pragma unroll
    for (int j = 0; j < 4; j++) rsum[m][j] = 0.f;
#pragma unroll
  for (int n = 0; n < 4; n++) csum[n] = 0.f;

  const int col16 = l & 15, rgp = (l >> 4) & 3;
  const bool diag = (rb == cb);
  const int growbase = wr * 128 + rgp * 4;
  const int gcolbase = wc * 64 + col16;
#pragma unroll
  for (int m = 0; m < 8; m++) {
#pragma unroll
    for (int n = 0; n < 4; n++) {
#pragma unroll
      for (int j = 0; j < 4; j++) {
        const float e = (diag && (growbase + m * 16 + j) == (gcolbase + n * 16))
                            ? 0.f
                            : exp2f(acc[m][n][j] * EXPSCALE);
        rsum[m][j] += e;
        csum[n] += e;
      }
    }
  }
#pragma unroll
  for (int m = 0; m < 8; m++)
#pragma unroll
    for (int j = 0; j < 4; j++) {
      float v = rsum[m][j];
      v += __shfl_xor(v, 1); v += __shfl_xor(v, 2);
      v += __shfl_xor(v, 4); v += __shfl_xor(v, 8);
      rsum[m][j] = v;
    }
#pragma unroll
  for (int n = 0; n < 4; n++) {
    float v = csum[n];
    v += __shfl_xor(v, 16); v += __shfl_xor(v, 32);
    csum[n] = v;
  }

  float* rS = (float*)smem;            // [4 wc][256 rows]
  float* cS = ((float*)smem) + 1024;   // [2 wr][256 cols]
  if (col16 == 0) {
#pragma unroll
    for (int m = 0; m < 8; m++)
#pragma unroll
      for (int j = 0; j < 4; j++)
        rS[wc * 256 + wr * 128 + m * 16 + rgp * 4 + j] = rsum[m][j];
  }
  if (rgp == 0) {
#pragma unroll
    for (int n = 0; n < 4; n++)
      cS[wr * 256 + wc * 64 + n * 16 + col16] = csum[n];
  }
  __syncthreads();
  // partial layout: [68 col-blocks of 128][8192 rows]
  if (t < 256) {
    const float rs_lo = rS[t] + rS[256 + t];
    const float rs_hi = rS[512 + t] + rS[768 + t];
    partial[(size_t)(cb * 2) * N2 + rb * 256 + t] = rs_lo;
    partial[(size_t)(cb * 2 + 1) * N2 + rb * 256 + t] = rs_hi;
    if (!diag) {
      partial[(size_t)(rb * 2) * N2 + cb * 256 + t] = cS[t];
      partial[(size_t)(rb * 2 + 1) * N2 + cb * 256 + t] = cS[256 + t];
    }
  }
}

// ---------------- Kernel Bt: tail — 128 eighth-tiles (64x128) of tiles (0,16..31) -------
// 8 waves (2M x 4N), wave tile 32x32, BK=128, 8 K-iters, 96 KiB LDS,
// prefetch distance 2 with correct parity + lgkm-drained buffer turnover.
#define TSG_A(ii, ktv, dst) gload16(reps + (tarow0 + (ii) * 32 + tsrow) * D + (ktv) * 128 + tschk * 8, \
                                    (dst) + (size_t)((ii) * 32 + w * 4) * 128)
#define TSG_B(ii, ktv, dst) gload16(reps + (tbrow0 + (ii) * 32 + tsrow) * D + (ktv) * 128 + tschk * 8, \
                                    (dst) + (size_t)((ii) * 32 + w * 4) * 128)

#define TRD(buf, row, kk) (*(const bf16x8*)((const char*)(buf) + (row) * 256 + \
                           ((((kk) * 4 + q4) ^ ((row) & 15)) << 4)))

#define TMFMA(kk)                                                       \
  __builtin_amdgcn_s_setprio(1);                                        \
  _Pragma("unroll") for (int m2 = 0; m2 < 2; m2++)                      \
  _Pragma("unroll") for (int n = 0; n < 2; n++)                         \
    acc[m2][n] = __builtin_amdgcn_mfma_f32_16x16x32_bf16(               \
        af[m2][kk], bf[n][kk], acc[m2][n], 0, 0, 0);                    \
  __builtin_amdgcn_s_setprio(0);

#define TTILE(tv, S, R, HASW, WV)                                       \
  {                                                                     \
    const int cur = (tv) & 1;                                           \
    const char* bA  = cur ? (const char*)tA1 : (const char*)tA0;        \
    const char* bB  = cur ? (const char*)tB1 : (const char*)tB0;        \
    const char* bAn = cur ? (const char*)tA0 : (const char*)tA1;        \
    const char* bBn = cur ? (const char*)tB0 : (const char*)tB1;        \
    short* stA = cur ? tA1 : tA0;   /* = bA buffer: parity(t+2) */      \
    short* stB = cur ? tB1 : tB0;                                       \
    /* ph1: read k-slices 2,3 of tile tv; MFMA k-slices 0,1 */          \
    _Pragma("unroll") for (int kk = 2; kk < 4; kk++) {                  \
      _Pragma("unroll") for (int m2 = 0; m2 < 2; m2++)                  \
        af[m2][kk] = TRD(bA, tarow_r + m2 * 16, kk);                    \
      _Pragma("unroll") for (int n = 0; n < 2; n++)                     \
        bf[n][kk] = TRD(bB, tbrow_r + n * 16, kk);                      \
    }                                                                   \
    TMFMA(0); TMFMA(1);                                                 \
    LGKM0();                                                            \
    BARRIER();                                                          \
    /* ph2: stage tile tv+2 into bA/bB buffers; MFMA k-slices 2,3 */    \
    if (S) { TSG_A(0, (tv) + 2, stA); TSG_A(1, (tv) + 2, stA);          \
             TSG_B(0, (tv) + 2, stB); TSG_B(1, (tv) + 2, stB);          \
             TSG_B(2, (tv) + 2, stB); TSG_B(3, (tv) + 2, stB); }        \
    TMFMA(2); TMFMA(3);                                                 \
    if (HASW) { WAITV(WV); }                                            \
    BARRIER();                                                          \
    /* R: read tile tv+1 k-slices 0,1 */                                \
    if (R) {                                                            \
      _Pragma("unroll") for (int kk = 0; kk < 2; kk++) {                \
        _Pragma("unroll") for (int m2 = 0; m2 < 2; m2++)                \
          af[m2][kk] = TRD(bAn, tarow_r + m2 * 16, kk);                 \
        _Pragma("unroll") for (int n = 0; n < 2; n++)                   \
          bf[n][kk] = TRD(bBn, tbrow_r + n * 16, kk);                   \
      }                                                                 \
    }                                                                   \
  }

__global__ __launch_bounds__(512) void kgemmt(const short* __restrict__ reps,
                                              float* __restrict__ partial) {
  extern __shared__ char smem[];
  short* tA0 = (short*)smem;                  // 16 KB [64][128]
  short* tA1 = (short*)(smem + 16384);
  short* tB0 = (short*)(smem + 32768);        // 32 KB [128][128]
  short* tB1 = (short*)(smem + 65536);

  const int b = (int)blockIdx.x;              // 0..127
  const int s = b >> 3, sub = b & 7;
  const int qr = sub >> 1;                    // 64-row chunk of rows 0..255
  const int qc = sub & 1;                     // 128-col half of the 256-col tile
  const int cbt = 16 + s;

  const int t = threadIdx.x;
  const int l = t & 63, w = t >> 6;
  const int wr = w >> 2, wc = w & 3;          // 2 x 4 wave grid

  f32x4 acc[2][2];
  const f32x4 zero4 = {0.f, 0.f, 0.f, 0.f};
#pragma unroll
  for (int m = 0; m < 2; m++)
#pragma unroll
    for (int n = 0; n < 2; n++) acc[m][n] = zero4;

  // staging: inst = 512 lanes x 16B = 32 rows x 256B
  const int tsrow = w * 4 + (l >> 4);          // row within 32-row inst chunk
  const int tschk = (l & 15) ^ (tsrow & 15);   // pre-swizzled source 16B chunk
  const size_t tarow0 = (size_t)qr * 64;
  const size_t tbrow0 = (size_t)cbt * 256 + (size_t)qc * 128;

  // read side
  const int q4 = (l >> 4) & 3;
  const int tarow_r = wr * 32 + (l & 15);
  const int tbrow_r = wc * 32 + (l & 15);

  // ---- prologue: stage tiles 0,1; retire tile 0; preload k-slices 0,1 ----
  TSG_A(0, 0, tA0); TSG_A(1, 0, tA0);
  TSG_B(0, 0, tB0); TSG_B(1, 0, tB0); TSG_B(2, 0, tB0); TSG_B(3, 0, tB0);
  TSG_A(0, 1, tA1); TSG_A(1, 1, tA1);
  TSG_B(0, 1, tB1); TSG_B(1, 1, tB1); TSG_B(2, 1, tB1); TSG_B(3, 1, tB1);
  WAITV(6);
  BARRIER();

  bf16x8 af[2][4], bf[2][4];
#pragma unroll
  for (int kk = 0; kk < 2; kk++) {
#pragma unroll
    for (int m2 = 0; m2 < 2; m2++) af[m2][kk] = TRD((const char*)tA0, tarow_r + m2 * 16, kk);
#pragma unroll
    for (int n = 0; n < 2; n++) bf[n][kk] = TRD((const char*)tB0, tbrow_r + n * 16, kk);
  }

#pragma unroll 1
  for (int tv = 0; tv < 6; ++tv) TTILE(tv, 1, 1, 1, 6)
  TTILE(6, 0, 1, 1, 0)
  TTILE(7, 0, 0, 0, 0)

  // -------- epilogue (no diagonal: rows < 256, cols >= 4096) --------
  float rsum[2][4];
  float csum[2];
#pragma unroll
  for (int m = 0; m < 2; m++)
#pragma unroll
    for (int j = 0; j < 4; j++) rsum[m][j] = 0.f;
  csum[0] = 0.f; csum[1] = 0.f;

#pragma unroll
  for (int m = 0; m < 2; m++)
#pragma unroll
    for (int n = 0; n < 2; n++)
#pragma unroll
      for (int j = 0; j < 4; j++) {
        const float e = exp2f(acc[m][n][j] * EXPSCALE);
        rsum[m][j] += e;
        csum[n] += e;
      }
#pragma unroll
  for (int m = 0; m < 2; m++)
#pragma unroll
    for (int j = 0; j < 4; j++) {
      float v = rsum[m][j];
      v += __shfl_xor(v, 1); v += __shfl_xor(v, 2);
      v += __shfl_xor(v, 4); v += __shfl_xor(v, 8);
      rsum[m][j] = v;
    }
#pragma unroll
  for (int n = 0; n < 2; n++) {
    float v = csum[n];
    v += __shfl_xor(v, 16); v += __shfl_xor(v, 32);
    csum[n] = v;
  }

  const int col16 = l & 15, rgp = (l >> 4) & 3;
  float* rS = (float*)smem;            // [4 wc][64 rows]
  float* cS = ((float*)smem) + 256;    // [2 wr][128 cols]
  if (col16 == 0) {
#pragma unroll
    for (int m = 0; m < 2; m++)
#pragma unroll
      for (int j = 0; j < 4; j++)
        rS[wc * 64 + wr * 32 + m * 16 + rgp * 4 + j] = rsum[m][j];
  }
  if (rgp == 0) {
#pragma unroll
    for (int n = 0; n < 2; n++)
      cS[wr * 128 + wc * 32 + n * 16 + col16] = csum[n];
  }
  __syncthreads();
  if (t < 64) {
    const float rs = rS[t] + rS[64 + t] + rS[128 + t] + rS[192 + t];
    partial[(size_t)(cbt * 2 + qc) * N2 + qr * 64 + t] = rs;
  }
  if (t < 128) {
    const float cs = cS[t] + cS[128 + t];
    partial[(size_t)(64 + qr) * N2 + cbt * 256 + qc * 128 + t] = cs;
  }
}

// ---------------- Kernel C1: per-row denom; log; block sum --------------------------------
__device__ inline float blockReduce(float v, float* sred) {
#pragma unroll
  for (int o = 32; o > 0; o >>= 1) v += __shfl_xor(v, o);
  const int lane = threadIdx.x & 63, wid = threadIdx.x >> 6;
  if (lane == 0) sred[wid] = v;
  __syncthreads();
  v = sred[0] + sred[1] + sred[2] + sred[3];
  __syncthreads();
  return v;
}

__global__ __launch_bounds__(256) void kred1(const float* __restrict__ partial,
                                             float* __restrict__ bsum) {
  const int r = blockIdx.x * 256 + threadIdx.x;
  float d = 0.f;
#pragma unroll 8
  for (int cbx = 0; cbx < 64; ++cbx) d += partial[(size_t)cbx * N2 + r];
  if (blockIdx.x >= 16) {   // rows >= 4096: add tail colsum slots 64..67
#pragma unroll
    for (int cbx = 64; cbx < 68; ++cbx) d += partial[(size_t)cbx * N2 + r];
  }
  float v = logf(d);
  __shared__ float sred[4];
  v = blockReduce(v, sred);
  if (threadIdx.x == 0) bsum[blockIdx.x] = v;
}

// ---------------- Kernel C2: final scalar -------------------------------------------------
__global__ __launch_bounds__(256) void kred2(const float* __restrict__ bsum,
                                             const float* __restrict__ pos,
                                             float* __restrict__ out) {
  const int t = threadIdx.x;
  float v = (t < 32) ? bsum[t] : 0.f;
  float p = 0.f;
  for (int k = t; k < BSZ; k += 256) p += pos[k];
  __shared__ float sred[4];
  v = blockReduce(v, sred);
  p = blockReduce(p, sred);
  if (t == 0) out[0] = (v - 2.0f * p / TEMPV) / (float)N2;
}

extern "C" void kernel_launch(void* const* d_in, const int* in_sizes, int n_in,
                              void* d_out, int out_size, void* d_ws, size_t ws_size,
                              hipStream_t stream) {
  const float* ei = (const float*)d_in[0];
  const float* ej = (const float*)d_in[1];
  char* ws = (char*)d_ws;
  unsigned short* reps = (unsigned short*)ws;                       // 16 MB bf16 [8192][1024]
  float* partial = (float*)(ws + (size_t)16 * 1024 * 1024);         // 2.18 MB [68][8192]
  float* pos = (float*)(ws + (size_t)16 * 1024 * 1024 + 2304 * 1024);   // 16 KB [4096]
  float* bsum = (float*)(ws + (size_t)16 * 1024 * 1024 + 2304 * 1024 + 16384); // 128 B

  (void)hipFuncSetAttribute((const void*)kgemm3,
                            hipFuncAttributeMaxDynamicSharedMemorySize, 65536);
  (void)hipFuncSetAttribute((const void*)kgemmt,
                            hipFuncAttributeMaxDynamicSharedMemorySize, 98304);

  knorm<<<BSZ, 256, 0, stream>>>(ei, ej, reps, pos);
  kgemm3<<<512, 512, 65536, stream>>>((const short*)reps, partial);
  kgemmt<<<128, 512, 98304, stream>>>((const short*)reps, partial);
  kred1<<<32, 256, 0, stream>>>(partial, bsum);
  kred2<<<1, 256, 0, stream>>>(bsum, pos, (float*)d_out);
}

// Round 9
// 90.781 us; speedup vs baseline: 1.5263x; 1.5263x over previous
//
#include <hip/hip_runtime.h>

#define BSZ 4096
#define D 1024
#define N2 8192
#define TEMPV 0.5f
// exp(x/T) = exp2(x * log2(e)/T)
#define EXPSCALE 2.8853900817779268f
#define NTB 32      // 8192 / 256 tiles per dim

typedef __attribute__((ext_vector_type(8))) short bf16x8;
typedef __attribute__((ext_vector_type(4))) float f32x4;

__device__ inline unsigned short f2bf(float x) {
  unsigned int u = __float_as_uint(x);
  u += 0x7fffu + ((u >> 16) & 1u);   // round-to-nearest-even
  return (unsigned short)(u >> 16);
}

// bit-exact float -> OCP e4m3fn, RNE (inputs |x|<=1 here; clamp kept for safety)
__device__ inline unsigned int f2e4m3(float x) {
  unsigned int u = __float_as_uint(x);
  const unsigned int s = (u >> 24) & 0x80u;
  u &= 0x7fffffffu;
  const float a = __uint_as_float(u);
  if (a >= 448.0f) return s | 0x7Eu;
  if (a < 0.015625f) {                       // < 2^-6: subnormal
    const int m = (int)rintf(a * 512.0f);    // RNE; 8 -> 0x08 == 2^-6 exactly
    return s | (unsigned int)m;
  }
  u += 0x7FFFFu + ((u >> 20) & 1u);          // RNE to 3 mantissa bits
  const unsigned int e = u >> 23;            // biased f32 exp (>=121)
  const unsigned int m3 = (u >> 20) & 7u;
  return s | (((e - 120u) << 3) | m3);       // e4m3 bias 7
}

__device__ inline void gload16(const void* g, void* l) {
  __builtin_amdgcn_global_load_lds(
      (const __attribute__((address_space(1))) void*)g,
      (__attribute__((address_space(3))) void*)l, 16, 0, 0);
}

// ---------------- Kernel A: L2-normalize rows, emit bf16 + fp8 reps + pos dot ----------
__global__ __launch_bounds__(256) void knorm(const float* __restrict__ ei,
                                             const float* __restrict__ ej,
                                             unsigned short* __restrict__ reps,
                                             unsigned char* __restrict__ reps8,
                                             float* __restrict__ pos) {
  const int r = blockIdx.x;
  const int t = threadIdx.x;
  const float4 vi = ((const float4*)(ei + (size_t)r * D))[t];
  const float4 vj = ((const float4*)(ej + (size_t)r * D))[t];
  float ssi = vi.x * vi.x + vi.y * vi.y + vi.z * vi.z + vi.w * vi.w;
  float ssj = vj.x * vj.x + vj.y * vj.y + vj.z * vj.z + vj.w * vj.w;
  float sij = vi.x * vj.x + vi.y * vj.y + vi.z * vj.z + vi.w * vj.w;
#pragma unroll
  for (int o = 32; o > 0; o >>= 1) {
    ssi += __shfl_xor(ssi, o);
    ssj += __shfl_xor(ssj, o);
    sij += __shfl_xor(sij, o);
  }
  __shared__ float red[12];
  const int lane = t & 63, wid = t >> 6;
  if (lane == 0) { red[wid * 3] = ssi; red[wid * 3 + 1] = ssj; red[wid * 3 + 2] = sij; }
  __syncthreads();
  ssi = red[0] + red[3] + red[6] + red[9];
  ssj = red[1] + red[4] + red[7] + red[10];
  sij = red[2] + red[5] + red[8] + red[11];
  const float inv_i = rsqrtf(fmaxf(ssi, 1e-24f));
  const float inv_j = rsqrtf(fmaxf(ssj, 1e-24f));
  const float xi0 = vi.x * inv_i, xi1 = vi.y * inv_i, xi2 = vi.z * inv_i, xi3 = vi.w * inv_i;
  const float xj0 = vj.x * inv_j, xj1 = vj.y * inv_j, xj2 = vj.z * inv_j, xj3 = vj.w * inv_j;
  ushort4 ui, uj;
  ui.x = f2bf(xi0); ui.y = f2bf(xi1); ui.z = f2bf(xi2); ui.w = f2bf(xi3);
  uj.x = f2bf(xj0); uj.y = f2bf(xj1); uj.z = f2bf(xj2); uj.w = f2bf(xj3);
  *((ushort4*)(reps + (size_t)r * D) + t) = ui;
  *((ushort4*)(reps + (size_t)(BSZ + r) * D) + t) = uj;
  const unsigned int pi = f2e4m3(xi0) | (f2e4m3(xi1) << 8) | (f2e4m3(xi2) << 16) | (f2e4m3(xi3) << 24);
  const unsigned int pj = f2e4m3(xj0) | (f2e4m3(xj1) << 8) | (f2e4m3(xj2) << 16) | (f2e4m3(xj3) << 24);
  *(unsigned int*)(reps8 + (size_t)r * 1024 + t * 4) = pi;
  *(unsigned int*)(reps8 + (size_t)(BSZ + r) * 1024 + t * 4) = pj;
  if (t == 0) pos[r] = sij * inv_i * inv_j;
}

// ======================= shared asm helpers =======================
#define BARRIER() do { __builtin_amdgcn_s_barrier(); asm volatile("" ::: "memory"); } while (0)
#define STR2(x) #x
#define WAITV(n) asm volatile("s_waitcnt vmcnt(" STR2(n) ")" ::: "memory")
#define LGKM0() asm volatile("s_waitcnt lgkmcnt(0)" ::: "memory")

// ---------------- Kernel B: 256x256 tiles (512 = 2 clean rounds), fp8 R5-engine ---------
// 8 waves (2M x 4N), wave tile 128x64, BK=64 fp8 (rows = 64B). LDS 64 KiB:
// A dbuf 2x16KB + B dbuf 2x16KB. 16B-granule XOR swizzle: LDS[row][c16] holds source
// chunk c16 ^ ((row>>1)&3)  (keeps gload16 src 16B-contiguous; read side XORs back).
// Ledger/tile (per thread: 2 A gloads @ph1 for t+1, 2 B gloads @ph3 for t+2):
//   steady-state outstanding at ph3-end = B(t+1)2 + A(t+1)2 + B(t+2)2 -> WAITV(2)
//   retires A(t+1),B(t+1) before ph4 reads them. kt=14: WAITV(0). Prologue: WAITV(2).
#define SG_A(ii, ktv, dst) gload16(reps8 + (size_t)(arow0 + (ii) * 128 + (t >> 2)) * 1024 + \
                                       (ktv) * 64 + (((t & 3) ^ ((t >> 3) & 3)) << 4),     \
                                   (dst) + (size_t)(ii) * 8192 + (size_t)t * 16)
#define SG_B(ii, ktv, dst) gload16(reps8 + (size_t)(brow0 + (ii) * 128 + (t >> 2)) * 1024 + \
                                       (ktv) * 64 + (((t & 3) ^ ((t >> 3) & 3)) << 4),     \
                                   (dst) + (size_t)(ii) * 8192 + (size_t)t * 16)

#define READ_AQ(buf, q) do {                                            \
    const char* r0_ = (buf) + (arow + (2 * (q)) * 16) * 64;             \
    const char* r1_ = (buf) + (arow + (2 * (q) + 1) * 16) * 64;         \
    af[0][0] = *(const long*)(r0_ + offA0);                             \
    af[0][1] = *(const long*)(r0_ + offA1);                             \
    af[1][0] = *(const long*)(r1_ + offA0);                             \
    af[1][1] = *(const long*)(r1_ + offA1);                             \
  } while (0)

#define READ_B2(buf, n) do {                                            \
    const char* rp_ = (buf) + (brow + (n) * 16) * 64;                   \
    bfr[n][0] = *(const long*)(rp_ + offB0);                            \
    bfr[n][1] = *(const long*)(rp_ + offB1);                            \
  } while (0)

// 16 MFMA; bfr[0..1] half first so ph1's fresh bfr[2..3] reads have cover.
#define MFMA_Q(q)                                                       \
  __builtin_amdgcn_s_setprio(1);                                        \
  _Pragma("unroll") for (int nh = 0; nh < 2; nh++)                      \
  _Pragma("unroll") for (int kk = 0; kk < 2; kk++)                      \
  _Pragma("unroll") for (int m2 = 0; m2 < 2; m2++)                      \
  _Pragma("unroll") for (int nn = 0; nn < 2; nn++) {                    \
    const int n_ = nh * 2 + nn;                                         \
    acc[2 * (q) + m2][n_] = __builtin_amdgcn_mfma_f32_16x16x32_fp8_fp8( \
        af[m2][kk], bfr[n_][kk], acc[2 * (q) + m2][n_], 0, 0, 0);       \
  }                                                                     \
  __builtin_amdgcn_s_setprio(0);

#define DO_TILE(ktv, SA, SB, RDN, HASW, WV)                             \
  {                                                                     \
    const int cur = (ktv) & 1;                                          \
    const char* bA  = cur ? lA1 : lA0;                                  \
    const char* bB  = cur ? lB1 : lB0;                                  \
    const char* bAn = cur ? lA0 : lA1;                                  \
    const char* bBn = cur ? lB0 : lB1;                                  \
    char* stA = (char*)(cur ? lA0 : lA1);                               \
    char* stB = (char*)(cur ? lB1 : lB0);                               \
    /* ph1: q0 MFMA (ops from prev ph4); read bfr[2..3](t) + Aq1; stage A(t+1) */ \
    READ_B2(bB, 2); READ_B2(bB, 3);                                     \
    MFMA_Q(0);                                                          \
    READ_AQ(bA, 1);                                                     \
    if (SA) { SG_A(0, (ktv) + 1, stA); SG_A(1, (ktv) + 1, stA); }       \
    BARRIER();                                                          \
    /* ph2 */                                                           \
    MFMA_Q(1);                                                          \
    READ_AQ(bA, 2);                                                     \
    BARRIER();                                                          \
    /* ph3: stage B(t+2); counted wait */                               \
    MFMA_Q(2);                                                          \
    READ_AQ(bA, 3);                                                     \
    if (SB) { SG_B(0, (ktv) + 2, stB); SG_B(1, (ktv) + 2, stB); }       \
    if (HASW) { WAITV(WV); }                                            \
    BARRIER();                                                          \
    /* ph4: read next tile's Aq0 + bfr[0..1] */                         \
    MFMA_Q(3);                                                          \
    if (RDN) { READ_AQ(bAn, 0); READ_B2(bBn, 0); READ_B2(bBn, 1); }     \
    BARRIER();                                                          \
  }

__global__ __launch_bounds__(512, 2) void kgemm3(const unsigned char* __restrict__ reps8,
                                                 float* __restrict__ partial) {
  extern __shared__ char smem[];
  char* lA0 = smem;                           // 16 KB  [256 rows][64 B]
  char* lA1 = smem + 16384;
  char* lB0 = smem + 32768;
  char* lB1 = smem + 49152;

  // XCD-aware swizzle (512 = 8 * 64, bijective), then decode into the
  // 512-tile list: triangle minus tiles (0, 16..31).
  int bid = (int)blockIdx.x;
  bid = (bid & 7) * 64 + (bid >> 3);
  int rb, cb;
  if (bid < 16) {
    rb = 0; cb = bid;
  } else {
    int rem = bid - 16;
    rb = 1;
    while (rem >= NTB - rb) { rem -= NTB - rb; rb++; }
    cb = rb + rem;
  }

  const int t = threadIdx.x;
  const int l = t & 63, w = t >> 6;
  const int wr = w >> 2, wc = w & 3;          // 2 x 4 wave grid

  f32x4 acc[8][4];
  const f32x4 zero4 = {0.f, 0.f, 0.f, 0.f};
#pragma unroll
  for (int m = 0; m < 8; m++)
#pragma unroll
    for (int n = 0; n < 4; n++) acc[m][n] = zero4;

  const size_t arow0 = (size_t)rb * 256;
  const size_t brow0 = (size_t)cb * 256;

  // read-side addressing: lane k-quarter q4 -> 8B at chunk8 = kk*4+q4 of the 64B row
  const int q4 = (l >> 4) & 3;
  const int lo8 = (q4 & 1) * 8;
  const int arow = wr * 128 + (l & 15);
  const int brow = wc * 64 + (l & 15);
  const int swzA = (arow >> 1) & 3;
  const int swzB = (brow >> 1) & 3;
  const int offA0 = ((((q4 >> 1)) ^ swzA) << 4) + lo8;
  const int offA1 = (((2 + (q4 >> 1)) ^ swzA) << 4) + lo8;
  const int offB0 = ((((q4 >> 1)) ^ swzB) << 4) + lo8;
  const int offB1 = (((2 + (q4 >> 1)) ^ swzB) << 4) + lo8;

  // ---- prologue: B(0), A(0), B(1); retire B(0)+A(0); preload tile-0 ph1 ops ----
  SG_B(0, 0, lB0); SG_B(1, 0, lB0);
  SG_A(0, 0, lA0); SG_A(1, 0, lA0);
  SG_B(0, 1, lB1); SG_B(1, 1, lB1);
  WAITV(2);
  BARRIER();

  long af[2][2], bfr[4][2];
  READ_AQ(lA0, 0);
  READ_B2(lB0, 0);
  READ_B2(lB0, 1);

#pragma unroll 1
  for (int kt = 0; kt < 14; ++kt) DO_TILE(kt, 1, 1, 1, 1, 2)
  DO_TILE(14, 1, 0, 1, 1, 0)
  DO_TILE(15, 0, 0, 0, 0, 0)

  // -------- epilogue: exp + diagonal mask + row/col partial sums --------
  float rsum[8][4];
  float csum[4];
#pragma unroll
  for (int m = 0; m < 8; m++)
#pragma unroll
    for (int j = 0; j < 4; j++) rsum[m][j] = 0.f;
#pragma unroll
  for (int n = 0; n < 4; n++) csum[n] = 0.f;

  const int col16 = l & 15, rgp = (l >> 4) & 3;
  const bool diag = (rb == cb);
  const int growbase = wr * 128 + rgp * 4;
  const int gcolbase = wc * 64 + col16;
#pragma unroll
  for (int m = 0; m < 8; m++) {
#pragma unroll
    for (int n = 0; n < 4; n++) {
#pragma unroll
      for (int j = 0; j < 4; j++) {
        const float e = (diag && (growbase + m * 16 + j) == (gcolbase + n * 16))
                            ? 0.f
                            : exp2f(acc[m][n][j] * EXPSCALE);
        rsum[m][j] += e;
        csum[n] += e;
      }
    }
  }
#pragma unroll
  for (int m = 0; m < 8; m++)
#pragma unroll
    for (int j = 0; j < 4; j++) {
      float v = rsum[m][j];
      v += __shfl_xor(v, 1); v += __shfl_xor(v, 2);
      v += __shfl_xor(v, 4); v += __shfl_xor(v, 8);
      rsum[m][j] = v;
    }
#pragma unroll
  for (int n = 0; n < 4; n++) {
    float v = csum[n];
    v += __shfl_xor(v, 16); v += __shfl_xor(v, 32);
    csum[n] = v;
  }

  float* rS = (float*)smem;            // [4 wc][256 rows]
  float* cS = ((float*)smem) + 1024;   // [2 wr][256 cols]
  if (col16 == 0) {
#pragma unroll
    for (int m = 0; m < 8; m++)
#pragma unroll
      for (int j = 0; j < 4; j++)
        rS[wc * 256 + wr * 128 + m * 16 + rgp * 4 + j] = rsum[m][j];
  }
  if (rgp == 0) {
#pragma unroll
    for (int n = 0; n < 4; n++)
      cS[wr * 256 + wc * 64 + n * 16 + col16] = csum[n];
  }
  __syncthreads();
  // partial layout: [68 col-blocks of 128][8192 rows]
  if (t < 256) {
    const float rs_lo = rS[t] + rS[256 + t];
    const float rs_hi = rS[512 + t] + rS[768 + t];
    partial[(size_t)(cb * 2) * N2 + rb * 256 + t] = rs_lo;
    partial[(size_t)(cb * 2 + 1) * N2 + rb * 256 + t] = rs_hi;
    if (!diag) {
      partial[(size_t)(rb * 2) * N2 + cb * 256 + t] = cS[t];
      partial[(size_t)(rb * 2 + 1) * N2 + cb * 256 + t] = cS[256 + t];
    }
  }
}

// ---------------- Kernel Bt: tail — 128 eighth-tiles (64x128) of tiles (0,16..31) -------
// bf16, unchanged from R7 (reads the bf16 reps copy).
#define TSG_A(ii, ktv, dst) gload16(reps + (tarow0 + (ii) * 32 + tsrow) * D + (ktv) * 128 + tschk * 8, \
                                    (dst) + (size_t)((ii) * 32 + w * 4) * 128)
#define TSG_B(ii, ktv, dst) gload16(reps + (tbrow0 + (ii) * 32 + tsrow) * D + (ktv) * 128 + tschk * 8, \
                                    (dst) + (size_t)((ii) * 32 + w * 4) * 128)

#define TRD(buf, row, kk) (*(const bf16x8*)((const char*)(buf) + (row) * 256 + \
                           ((((kk) * 4 + q4) ^ ((row) & 15)) << 4)))

#define TMFMA(kk)                                                       \
  __builtin_amdgcn_s_setprio(1);                                        \
  _Pragma("unroll") for (int m2 = 0; m2 < 2; m2++)                      \
  _Pragma("unroll") for (int n = 0; n < 2; n++)                         \
    acc[m2][n] = __builtin_amdgcn_mfma_f32_16x16x32_bf16(               \
        af[m2][kk], bf[n][kk], acc[m2][n], 0, 0, 0);                    \
  __builtin_amdgcn_s_setprio(0);

#define TTILE(tv, S, R, HASW, WV)                                       \
  {                                                                     \
    const int cur = (tv) & 1;                                           \
    const char* bA  = cur ? (const char*)tA1 : (const char*)tA0;        \
    const char* bB  = cur ? (const char*)tB1 : (const char*)tB0;        \
    const char* bAn = cur ? (const char*)tA0 : (const char*)tA1;        \
    const char* bBn = cur ? (const char*)tB0 : (const char*)tB1;        \
    short* stA = cur ? tA1 : tA0;   /* = bA buffer: parity(t+2) */      \
    short* stB = cur ? tB1 : tB0;                                       \
    _Pragma("unroll") for (int kk = 2; kk < 4; kk++) {                  \
      _Pragma("unroll") for (int m2 = 0; m2 < 2; m2++)                  \
        af[m2][kk] = TRD(bA, tarow_r + m2 * 16, kk);                    \
      _Pragma("unroll") for (int n = 0; n < 2; n++)                     \
        bf[n][kk] = TRD(bB, tbrow_r + n * 16, kk);                      \
    }                                                                   \
    TMFMA(0); TMFMA(1);                                                 \
    LGKM0();                                                            \
    BARRIER();                                                          \
    if (S) { TSG_A(0, (tv) + 2, stA); TSG_A(1, (tv) + 2, stA);          \
             TSG_B(0, (tv) + 2, stB); TSG_B(1, (tv) + 2, stB);          \
             TSG_B(2, (tv) + 2, stB); TSG_B(3, (tv) + 2, stB); }        \
    TMFMA(2); TMFMA(3);                                                 \
    if (HASW) { WAITV(WV); }                                            \
    BARRIER();                                                          \
    if (R) {                                                            \
      _Pragma("unroll") for (int kk = 0; kk < 2; kk++) {                \
        _Pragma("unroll") for (int m2 = 0; m2 < 2; m2++)                \
          af[m2][kk] = TRD(bAn, tarow_r + m2 * 16, kk);                 \
        _Pragma("unroll") for (int n = 0; n < 2; n++)                   \
          bf[n][kk] = TRD(bBn, tbrow_r + n * 16, kk);                   \
      }                                                                 \
    }                                                                   \
  }

__global__ __launch_bounds__(512) void kgemmt(const short* __restrict__ reps,
                                              float* __restrict__ partial) {
  extern __shared__ char smem[];
  short* tA0 = (short*)smem;                  // 16 KB [64][128]
  short* tA1 = (short*)(smem + 16384);
  short* tB0 = (short*)(smem + 32768);        // 32 KB [128][128]
  short* tB1 = (short*)(smem + 65536);

  const int b = (int)blockIdx.x;              // 0..127
  const int s = b >> 3, sub = b & 7;
  const int qr = sub >> 1;                    // 64-row chunk of rows 0..255
  const int qc = sub & 1;                     // 128-col half of the 256-col tile
  const int cbt = 16 + s;

  const int t = threadIdx.x;
  const int l = t & 63, w = t >> 6;
  const int wr = w >> 2, wc = w & 3;          // 2 x 4 wave grid

  f32x4 acc[2][2];
  const f32x4 zero4 = {0.f, 0.f, 0.f, 0.f};
#pragma unroll
  for (int m = 0; m < 2; m++)
#pragma unroll
    for (int n = 0; n < 2; n++) acc[m][n] = zero4;

  const int tsrow = w * 4 + (l >> 4);          // row within 32-row inst chunk
  const int tschk = (l & 15) ^ (tsrow & 15);   // pre-swizzled source 16B chunk
  const size_t tarow0 = (size_t)qr * 64;
  const size_t tbrow0 = (size_t)cbt * 256 + (size_t)qc * 128;

  const int q4 = (l >> 4) & 3;
  const int tarow_r = wr * 32 + (l & 15);
  const int tbrow_r = wc * 32 + (l & 15);

  TSG_A(0, 0, tA0); TSG_A(1, 0, tA0);
  TSG_B(0, 0, tB0); TSG_B(1, 0, tB0); TSG_B(2, 0, tB0); TSG_B(3, 0, tB0);
  TSG_A(0, 1, tA1); TSG_A(1, 1, tA1);
  TSG_B(0, 1, tB1); TSG_B(1, 1, tB1); TSG_B(2, 1, tB1); TSG_B(3, 1, tB1);
  WAITV(6);
  BARRIER();

  bf16x8 af[2][4], bf[2][4];
#pragma unroll
  for (int kk = 0; kk < 2; kk++) {
#pragma unroll
    for (int m2 = 0; m2 < 2; m2++) af[m2][kk] = TRD((const char*)tA0, tarow_r + m2 * 16, kk);
#pragma unroll
    for (int n = 0; n < 2; n++) bf[n][kk] = TRD((const char*)tB0, tbrow_r + n * 16, kk);
  }

#pragma unroll 1
  for (int tv = 0; tv < 6; ++tv) TTILE(tv, 1, 1, 1, 6)
  TTILE(6, 0, 1, 1, 0)
  TTILE(7, 0, 0, 0, 0)

  float rsum[2][4];
  float csum[2];
#pragma unroll
  for (int m = 0; m < 2; m++)
#pragma unroll
    for (int j = 0; j < 4; j++) rsum[m][j] = 0.f;
  csum[0] = 0.f; csum[1] = 0.f;

#pragma unroll
  for (int m = 0; m < 2; m++)
#pragma unroll
    for (int n = 0; n < 2; n++)
#pragma unroll
      for (int j = 0; j < 4; j++) {
        const float e = exp2f(acc[m][n][j] * EXPSCALE);
        rsum[m][j] += e;
        csum[n] += e;
      }
#pragma unroll
  for (int m = 0; m < 2; m++)
#pragma unroll
    for (int j = 0; j < 4; j++) {
      float v = rsum[m][j];
      v += __shfl_xor(v, 1); v += __shfl_xor(v, 2);
      v += __shfl_xor(v, 4); v += __shfl_xor(v, 8);
      rsum[m][j] = v;
    }
#pragma unroll
  for (int n = 0; n < 2; n++) {
    float v = csum[n];
    v += __shfl_xor(v, 16); v += __shfl_xor(v, 32);
    csum[n] = v;
  }

  const int col16 = l & 15, rgp = (l >> 4) & 3;
  float* rS = (float*)smem;            // [4 wc][64 rows]
  float* cS = ((float*)smem) + 256;    // [2 wr][128 cols]
  if (col16 == 0) {
#pragma unroll
    for (int m = 0; m < 2; m++)
#pragma unroll
      for (int j = 0; j < 4; j++)
        rS[wc * 64 + wr * 32 + m * 16 + rgp * 4 + j] = rsum[m][j];
  }
  if (rgp == 0) {
#pragma unroll
    for (int n = 0; n < 2; n++)
      cS[wr * 128 + wc * 32 + n * 16 + col16] = csum[n];
  }
  __syncthreads();
  if (t < 64) {
    const float rs = rS[t] + rS[64 + t] + rS[128 + t] + rS[192 + t];
    partial[(size_t)(cbt * 2 + qc) * N2 + qr * 64 + t] = rs;
  }
  if (t < 128) {
    const float cs = cS[t] + cS[128 + t];
    partial[(size_t)(64 + qr) * N2 + cbt * 256 + qc * 128 + t] = cs;
  }
}

// ---------------- Kernel C1: per-row denom; log; block sum --------------------------------
__device__ inline float blockReduce(float v, float* sred) {
#pragma unroll
  for (int o = 32; o > 0; o >>= 1) v += __shfl_xor(v, o);
  const int lane = threadIdx.x & 63, wid = threadIdx.x >> 6;
  if (lane == 0) sred[wid] = v;
  __syncthreads();
  v = sred[0] + sred[1] + sred[2] + sred[3];
  __syncthreads();
  return v;
}

__global__ __launch_bounds__(256) void kred1(const float* __restrict__ partial,
                                             float* __restrict__ bsum) {
  const int r = blockIdx.x * 256 + threadIdx.x;
  float d = 0.f;
#pragma unroll 8
  for (int cbx = 0; cbx < 64; ++cbx) d += partial[(size_t)cbx * N2 + r];
  if (blockIdx.x >= 16) {   // rows >= 4096: add tail colsum slots 64..67
#pragma unroll
    for (int cbx = 64; cbx < 68; ++cbx) d += partial[(size_t)cbx * N2 + r];
  }
  float v = logf(d);
  __shared__ float sred[4];
  v = blockReduce(v, sred);
  if (threadIdx.x == 0) bsum[blockIdx.x] = v;
}

// ---------------- Kernel C2: final scalar -------------------------------------------------
__global__ __launch_bounds__(256) void kred2(const float* __restrict__ bsum,
                                             const float* __restrict__ pos,
                                             float* __restrict__ out) {
  const int t = threadIdx.x;
  float v = (t < 32) ? bsum[t] : 0.f;
  float p = 0.f;
  for (int k = t; k < BSZ; k += 256) p += pos[k];
  __shared__ float sred[4];
  v = blockReduce(v, sred);
  p = blockReduce(p, sred);
  if (t == 0) out[0] = (v - 2.0f * p / TEMPV) / (float)N2;
}

extern "C" void kernel_launch(void* const* d_in, const int* in_sizes, int n_in,
                              void* d_out, int out_size, void* d_ws, size_t ws_size,
                              hipStream_t stream) {
  const float* ei = (const float*)d_in[0];
  const float* ej = (const float*)d_in[1];
  char* ws = (char*)d_ws;
  unsigned short* reps = (unsigned short*)ws;                          // 16 MB bf16 [8192][1024]
  unsigned char* reps8 = (unsigned char*)(ws + (size_t)16 * 1024 * 1024); // 8 MB fp8 [8192][1024]
  float* partial = (float*)(ws + (size_t)24 * 1024 * 1024);            // 2.13 MB [68][8192]
  float* pos = (float*)(ws + (size_t)24 * 1024 * 1024 + 2304 * 1024);  // 16 KB [4096]
  float* bsum = (float*)(ws + (size_t)24 * 1024 * 1024 + 2304 * 1024 + 16384); // 128 B

  (void)hipFuncSetAttribute((const void*)kgemm3,
                            hipFuncAttributeMaxDynamicSharedMemorySize, 65536);
  (void)hipFuncSetAttribute((const void*)kgemmt,
                            hipFuncAttributeMaxDynamicSharedMemorySize, 98304);

  knorm<<<BSZ, 256, 0, stream>>>(ei, ej, reps, reps8, pos);
  kgemm3<<<512, 512, 65536, stream>>>(reps8, partial);
  kgemmt<<<128, 512, 98304, stream>>>((const short*)reps, partial);
  kred1<<<32, 256, 0, stream>>>(partial, bsum);
  kred2<<<1, 256, 0, stream>>>(bsum, pos, (float*)d_out);
}

// Round 10
// 87.479 us; speedup vs baseline: 1.5839x; 1.0378x over previous
//
#include <hip/hip_runtime.h>

#define BSZ 4096
#define D 1024
#define N2 8192
#define TEMPV 0.5f
// exp(x/T) = exp2(x * log2(e)/T)
#define EXPSCALE 2.8853900817779268f
#define NTB 32      // 8192 / 256 tiles per dim

typedef __attribute__((ext_vector_type(8))) short bf16x8;
typedef __attribute__((ext_vector_type(4))) float f32x4;
typedef __attribute__((ext_vector_type(2))) long l64x2;

__device__ inline unsigned short f2bf(float x) {
  unsigned int u = __float_as_uint(x);
  u += 0x7fffu + ((u >> 16) & 1u);   // round-to-nearest-even
  return (unsigned short)(u >> 16);
}

// bit-exact float -> OCP e4m3fn, RNE (inputs |x|<=1 here; clamp kept for safety)
__device__ inline unsigned int f2e4m3(float x) {
  unsigned int u = __float_as_uint(x);
  const unsigned int s = (u >> 24) & 0x80u;
  u &= 0x7fffffffu;
  const float a = __uint_as_float(u);
  if (a >= 448.0f) return s | 0x7Eu;
  if (a < 0.015625f) {                       // < 2^-6: subnormal
    const int m = (int)rintf(a * 512.0f);    // RNE; 8 -> 0x08 == 2^-6 exactly
    return s | (unsigned int)m;
  }
  u += 0x7FFFFu + ((u >> 20) & 1u);          // RNE to 3 mantissa bits
  const unsigned int e = u >> 23;            // biased f32 exp (>=121)
  const unsigned int m3 = (u >> 20) & 7u;
  return s | (((e - 120u) << 3) | m3);       // e4m3 bias 7
}

__device__ inline void gload16(const void* g, void* l) {
  __builtin_amdgcn_global_load_lds(
      (const __attribute__((address_space(1))) void*)g,
      (__attribute__((address_space(3))) void*)l, 16, 0, 0);
}

// ---------------- Kernel A: L2-normalize rows, emit bf16 + k-permuted fp8 reps ----------
// fp8 layout: within each 64B k-group, 8B units stored in order [0,4,1,5,2,6,3,7]
// so that original units (q4, 4+q4) form one aligned 16B chunk q4 -> b128 LDS reads.
__global__ __launch_bounds__(256) void knorm(const float* __restrict__ ei,
                                             const float* __restrict__ ej,
                                             unsigned short* __restrict__ reps,
                                             unsigned char* __restrict__ reps8,
                                             float* __restrict__ pos) {
  const int r = blockIdx.x;
  const int t = threadIdx.x;
  const float4 vi = ((const float4*)(ei + (size_t)r * D))[t];
  const float4 vj = ((const float4*)(ej + (size_t)r * D))[t];
  float ssi = vi.x * vi.x + vi.y * vi.y + vi.z * vi.z + vi.w * vi.w;
  float ssj = vj.x * vj.x + vj.y * vj.y + vj.z * vj.z + vj.w * vj.w;
  float sij = vi.x * vj.x + vi.y * vj.y + vi.z * vj.z + vi.w * vj.w;
#pragma unroll
  for (int o = 32; o > 0; o >>= 1) {
    ssi += __shfl_xor(ssi, o);
    ssj += __shfl_xor(ssj, o);
    sij += __shfl_xor(sij, o);
  }
  __shared__ float red[12];
  const int lane = t & 63, wid = t >> 6;
  if (lane == 0) { red[wid * 3] = ssi; red[wid * 3 + 1] = ssj; red[wid * 3 + 2] = sij; }
  __syncthreads();
  ssi = red[0] + red[3] + red[6] + red[9];
  ssj = red[1] + red[4] + red[7] + red[10];
  sij = red[2] + red[5] + red[8] + red[11];
  const float inv_i = rsqrtf(fmaxf(ssi, 1e-24f));
  const float inv_j = rsqrtf(fmaxf(ssj, 1e-24f));
  const float xi0 = vi.x * inv_i, xi1 = vi.y * inv_i, xi2 = vi.z * inv_i, xi3 = vi.w * inv_i;
  const float xj0 = vj.x * inv_j, xj1 = vj.y * inv_j, xj2 = vj.z * inv_j, xj3 = vj.w * inv_j;
  ushort4 ui, uj;
  ui.x = f2bf(xi0); ui.y = f2bf(xi1); ui.z = f2bf(xi2); ui.w = f2bf(xi3);
  uj.x = f2bf(xj0); uj.y = f2bf(xj1); uj.z = f2bf(xj2); uj.w = f2bf(xj3);
  *((ushort4*)(reps + (size_t)r * D) + t) = ui;
  *((ushort4*)(reps + (size_t)(BSZ + r) * D) + t) = uj;
  const unsigned int pi = f2e4m3(xi0) | (f2e4m3(xi1) << 8) | (f2e4m3(xi2) << 16) | (f2e4m3(xi3) << 24);
  const unsigned int pj = f2e4m3(xj0) | (f2e4m3(xj1) << 8) | (f2e4m3(xj2) << 16) | (f2e4m3(xj3) << 24);
  // permuted destination: group g (64B), unit u (8B), half h (4B)
  const int g = t >> 4, j4 = t & 15;
  const int u = j4 >> 1, h = j4 & 1;
  const int up = (u < 4) ? (2 * u) : (2 * u - 7);   // [0,4,1,5,2,6,3,7] slotting
  const int noff = g * 64 + up * 8 + h * 4;
  *(unsigned int*)(reps8 + (size_t)r * 1024 + noff) = pi;
  *(unsigned int*)(reps8 + (size_t)(BSZ + r) * 1024 + noff) = pj;
  if (t == 0) pos[r] = sij * inv_i * inv_j;
}

// ======================= shared asm helpers =======================
#define BARRIER() do { __builtin_amdgcn_s_barrier(); asm volatile("" ::: "memory"); } while (0)
#define STR2(x) #x
#define WAITV(n) asm volatile("s_waitcnt vmcnt(" STR2(n) ")" ::: "memory")
#define LGKM0() asm volatile("s_waitcnt lgkmcnt(0)" ::: "memory")

// ---------------- Kernel B: 256x256 tiles (512 = 2 clean rounds), fp8 b128 engine -------
// 8 waves (2M x 4N), wave tile 128x64, BK=64 fp8 (rows = 64B, k-permuted). LDS 64 KiB.
// Each operand load = one ds_read_b128 at 16B chunk (q4 ^ ((row>>1)&3)) -> conflict-free
// (2-way only). Ledger/tile: 2 A gloads @ph1 (t+1), 2 B gloads @ph3 (t+2); WAITV(2)
// at ph3-end retires A(t+1)+B(t+1); kt=14 WAITV(0); prologue WAITV(2).
#define SG_A(ii, ktv, dst) gload16(reps8 + (size_t)(arow0 + (ii) * 128 + (t >> 2)) * 1024 + \
                                       (ktv) * 64 + (((t & 3) ^ ((t >> 3) & 3)) << 4),     \
                                   (dst) + (size_t)(ii) * 8192 + (size_t)t * 16)
#define SG_B(ii, ktv, dst) gload16(reps8 + (size_t)(brow0 + (ii) * 128 + (t >> 2)) * 1024 + \
                                       (ktv) * 64 + (((t & 3) ^ ((t >> 3) & 3)) << 4),     \
                                   (dst) + (size_t)(ii) * 8192 + (size_t)t * 16)

#define READ_AQ(buf, q) do {                                            \
    afp[0] = *(const l64x2*)((buf) + (arow + (2 * (q)) * 16) * 64 + offA);     \
    afp[1] = *(const l64x2*)((buf) + (arow + (2 * (q) + 1) * 16) * 64 + offA); \
  } while (0)

#define READ_B2(buf, n) do {                                            \
    bfp[n] = *(const l64x2*)((buf) + (brow + (n) * 16) * 64 + offB);    \
  } while (0)

// 16 MFMA; bfp[0..1] half first so ph1's fresh bfp[2..3] reads have cover.
#define MFMA_Q(q)                                                       \
  __builtin_amdgcn_s_setprio(1);                                        \
  _Pragma("unroll") for (int nh = 0; nh < 2; nh++)                      \
  _Pragma("unroll") for (int kk = 0; kk < 2; kk++)                      \
  _Pragma("unroll") for (int m2 = 0; m2 < 2; m2++)                      \
  _Pragma("unroll") for (int nn = 0; nn < 2; nn++) {                    \
    const int n_ = nh * 2 + nn;                                         \
    acc[2 * (q) + m2][n_] = __builtin_amdgcn_mfma_f32_16x16x32_fp8_fp8( \
        afp[m2][kk], bfp[n_][kk], acc[2 * (q) + m2][n_], 0, 0, 0);      \
  }                                                                     \
  __builtin_amdgcn_s_setprio(0);

#define DO_TILE(ktv, SA, SB, RDN, HASW, WV)                             \
  {                                                                     \
    const int cur = (ktv) & 1;                                          \
    const char* bA  = cur ? lA1 : lA0;                                  \
    const char* bB  = cur ? lB1 : lB0;                                  \
    const char* bAn = cur ? lA0 : lA1;                                  \
    const char* bBn = cur ? lB0 : lB1;                                  \
    char* stA = (char*)(cur ? lA0 : lA1);                               \
    char* stB = (char*)(cur ? lB1 : lB0);                               \
    /* ph1: q0 MFMA (ops from prev ph4); read bfp[2..3](t) + Aq1; stage A(t+1) */ \
    READ_B2(bB, 2); READ_B2(bB, 3);                                     \
    MFMA_Q(0);                                                          \
    READ_AQ(bA, 1);                                                     \
    if (SA) { SG_A(0, (ktv) + 1, stA); SG_A(1, (ktv) + 1, stA); }       \
    BARRIER();                                                          \
    /* ph2 */                                                           \
    MFMA_Q(1);                                                          \
    READ_AQ(bA, 2);                                                     \
    BARRIER();                                                          \
    /* ph3: stage B(t+2); counted wait */                               \
    MFMA_Q(2);                                                          \
    READ_AQ(bA, 3);                                                     \
    if (SB) { SG_B(0, (ktv) + 2, stB); SG_B(1, (ktv) + 2, stB); }       \
    if (HASW) { WAITV(WV); }                                            \
    BARRIER();                                                          \
    /* ph4: read next tile's Aq0 + bfp[0..1] */                         \
    MFMA_Q(3);                                                          \
    if (RDN) { READ_AQ(bAn, 0); READ_B2(bBn, 0); READ_B2(bBn, 1); }     \
    BARRIER();                                                          \
  }

__global__ __launch_bounds__(512, 2) void kgemm3(const unsigned char* __restrict__ reps8,
                                                 float* __restrict__ partial) {
  extern __shared__ char smem[];
  char* lA0 = smem;                           // 16 KB  [256 rows][64 B]
  char* lA1 = smem + 16384;
  char* lB0 = smem + 32768;
  char* lB1 = smem + 49152;

  // XCD-aware swizzle (512 = 8 * 64, bijective), then decode into the
  // 512-tile list: triangle minus tiles (0, 16..31).
  int bid = (int)blockIdx.x;
  bid = (bid & 7) * 64 + (bid >> 3);
  int rb, cb;
  if (bid < 16) {
    rb = 0; cb = bid;
  } else {
    int rem = bid - 16;
    rb = 1;
    while (rem >= NTB - rb) { rem -= NTB - rb; rb++; }
    cb = rb + rem;
  }

  const int t = threadIdx.x;
  const int l = t & 63, w = t >> 6;
  const int wr = w >> 2, wc = w & 3;          // 2 x 4 wave grid

  f32x4 acc[8][4];
  const f32x4 zero4 = {0.f, 0.f, 0.f, 0.f};
#pragma unroll
  for (int m = 0; m < 8; m++)
#pragma unroll
    for (int n = 0; n < 4; n++) acc[m][n] = zero4;

  const size_t arow0 = (size_t)rb * 256;
  const size_t brow0 = (size_t)cb * 256;

  // read-side addressing: one b128 per operand at chunk q4 ^ ((row>>1)&3)
  const int q4 = (l >> 4) & 3;
  const int arow = wr * 128 + (l & 15);
  const int brow = wc * 64 + (l & 15);
  const int offA = ((q4 ^ ((arow >> 1) & 3)) << 4);
  const int offB = ((q4 ^ ((brow >> 1) & 3)) << 4);

  // ---- prologue: B(0), A(0), B(1); retire B(0)+A(0); preload tile-0 ph1 ops ----
  SG_B(0, 0, lB0); SG_B(1, 0, lB0);
  SG_A(0, 0, lA0); SG_A(1, 0, lA0);
  SG_B(0, 1, lB1); SG_B(1, 1, lB1);
  WAITV(2);
  BARRIER();

  l64x2 afp[2], bfp[4];
  READ_AQ(lA0, 0);
  READ_B2(lB0, 0);
  READ_B2(lB0, 1);

#pragma unroll 1
  for (int kt = 0; kt < 14; ++kt) DO_TILE(kt, 1, 1, 1, 1, 2)
  DO_TILE(14, 1, 0, 1, 1, 0)
  DO_TILE(15, 0, 0, 0, 0, 0)

  // -------- epilogue: exp + diagonal mask + row/col partial sums --------
  float rsum[8][4];
  float csum[4];
#pragma unroll
  for (int m = 0; m < 8; m++)
#pragma unroll
    for (int j = 0; j < 4; j++) rsum[m][j] = 0.f;
#pragma unroll
  for (int n = 0; n < 4; n++) csum[n] = 0.f;

  const int col16 = l & 15, rgp = (l >> 4) & 3;
  const bool diag = (rb == cb);
  const int growbase = wr * 128 + rgp * 4;
  const int gcolbase = wc * 64 + col16;
#pragma unroll
  for (int m = 0; m < 8; m++) {
#pragma unroll
    for (int n = 0; n < 4; n++) {
#pragma unroll
      for (int j = 0; j < 4; j++) {
        const float e = (diag && (growbase + m * 16 + j) == (gcolbase + n * 16))
                            ? 0.f
                            : exp2f(acc[m][n][j] * EXPSCALE);
        rsum[m][j] += e;
        csum[n] += e;
      }
    }
  }
#pragma unroll
  for (int m = 0; m < 8; m++)
#pragma unroll
    for (int j = 0; j < 4; j++) {
      float v = rsum[m][j];
      v += __shfl_xor(v, 1); v += __shfl_xor(v, 2);
      v += __shfl_xor(v, 4); v += __shfl_xor(v, 8);
      rsum[m][j] = v;
    }
#pragma unroll
  for (int n = 0; n < 4; n++) {
    float v = csum[n];
    v += __shfl_xor(v, 16); v += __shfl_xor(v, 32);
    csum[n] = v;
  }

  float* rS = (float*)smem;            // [4 wc][256 rows]
  float* cS = ((float*)smem) + 1024;   // [2 wr][256 cols]
  if (col16 == 0) {
#pragma unroll
    for (int m = 0; m < 8; m++)
#pragma unroll
      for (int j = 0; j < 4; j++)
        rS[wc * 256 + wr * 128 + m * 16 + rgp * 4 + j] = rsum[m][j];
  }
  if (rgp == 0) {
#pragma unroll
    for (int n = 0; n < 4; n++)
      cS[wr * 256 + wc * 64 + n * 16 + col16] = csum[n];
  }
  __syncthreads();
  // partial layout: [68 col-blocks of 128][8192 rows]
  if (t < 256) {
    const float rs_lo = rS[t] + rS[256 + t];
    const float rs_hi = rS[512 + t] + rS[768 + t];
    partial[(size_t)(cb * 2) * N2 + rb * 256 + t] = rs_lo;
    partial[(size_t)(cb * 2 + 1) * N2 + rb * 256 + t] = rs_hi;
    if (!diag) {
      partial[(size_t)(rb * 2) * N2 + cb * 256 + t] = cS[t];
      partial[(size_t)(rb * 2 + 1) * N2 + cb * 256 + t] = cS[256 + t];
    }
  }
}

// ---------------- Kernel Bt: tail — 128 eighth-tiles (64x128) of tiles (0,16..31) -------
// bf16, unchanged (reads the bf16 reps copy).
#define TSG_A(ii, ktv, dst) gload16(reps + (tarow0 + (ii) * 32 + tsrow) * D + (ktv) * 128 + tschk * 8, \
                                    (dst) + (size_t)((ii) * 32 + w * 4) * 128)
#define TSG_B(ii, ktv, dst) gload16(reps + (tbrow0 + (ii) * 32 + tsrow) * D + (ktv) * 128 + tschk * 8, \
                                    (dst) + (size_t)((ii) * 32 + w * 4) * 128)

#define TRD(buf, row, kk) (*(const bf16x8*)((const char*)(buf) + (row) * 256 + \
                           ((((kk) * 4 + q4) ^ ((row) & 15)) << 4)))

#define TMFMA(kk)                                                       \
  __builtin_amdgcn_s_setprio(1);                                        \
  _Pragma("unroll") for (int m2 = 0; m2 < 2; m2++)                      \
  _Pragma("unroll") for (int n = 0; n < 2; n++)                         \
    acc[m2][n] = __builtin_amdgcn_mfma_f32_16x16x32_bf16(               \
        af[m2][kk], bf[n][kk], acc[m2][n], 0, 0, 0);                    \
  __builtin_amdgcn_s_setprio(0);

#define TTILE(tv, S, R, HASW, WV)                                       \
  {                                                                     \
    const int cur = (tv) & 1;                                           \
    const char* bA  = cur ? (const char*)tA1 : (const char*)tA0;        \
    const char* bB  = cur ? (const char*)tB1 : (const char*)tB0;        \
    const char* bAn = cur ? (const char*)tA0 : (const char*)tA1;        \
    const char* bBn = cur ? (const char*)tB0 : (const char*)tB1;        \
    short* stA = cur ? tA1 : tA0;   /* = bA buffer: parity(t+2) */      \
    short* stB = cur ? tB1 : tB0;                                       \
    _Pragma("unroll") for (int kk = 2; kk < 4; kk++) {                  \
      _Pragma("unroll") for (int m2 = 0; m2 < 2; m2++)                  \
        af[m2][kk] = TRD(bA, tarow_r + m2 * 16, kk);                    \
      _Pragma("unroll") for (int n = 0; n < 2; n++)                     \
        bf[n][kk] = TRD(bB, tbrow_r + n * 16, kk);                      \
    }                                                                   \
    TMFMA(0); TMFMA(1);                                                 \
    LGKM0();                                                            \
    BARRIER();                                                          \
    if (S) { TSG_A(0, (tv) + 2, stA); TSG_A(1, (tv) + 2, stA);          \
             TSG_B(0, (tv) + 2, stB); TSG_B(1, (tv) + 2, stB);          \
             TSG_B(2, (tv) + 2, stB); TSG_B(3, (tv) + 2, stB); }        \
    TMFMA(2); TMFMA(3);                                                 \
    if (HASW) { WAITV(WV); }                                            \
    BARRIER();                                                          \
    if (R) {                                                            \
      _Pragma("unroll") for (int kk = 0; kk < 2; kk++) {                \
        _Pragma("unroll") for (int m2 = 0; m2 < 2; m2++)                \
          af[m2][kk] = TRD(bAn, tarow_r + m2 * 16, kk);                 \
        _Pragma("unroll") for (int n = 0; n < 2; n++)                   \
          bf[n][kk] = TRD(bBn, tbrow_r + n * 16, kk);                   \
      }                                                                 \
    }                                                                   \
  }

__global__ __launch_bounds__(512) void kgemmt(const short* __restrict__ reps,
                                              float* __restrict__ partial) {
  extern __shared__ char smem[];
  short* tA0 = (short*)smem;                  // 16 KB [64][128]
  short* tA1 = (short*)(smem + 16384);
  short* tB0 = (short*)(smem + 32768);        // 32 KB [128][128]
  short* tB1 = (short*)(smem + 65536);

  const int b = (int)blockIdx.x;              // 0..127
  const int s = b >> 3, sub = b & 7;
  const int qr = sub >> 1;                    // 64-row chunk of rows 0..255
  const int qc = sub & 1;                     // 128-col half of the 256-col tile
  const int cbt = 16 + s;

  const int t = threadIdx.x;
  const int l = t & 63, w = t >> 6;
  const int wr = w >> 2, wc = w & 3;          // 2 x 4 wave grid

  f32x4 acc[2][2];
  const f32x4 zero4 = {0.f, 0.f, 0.f, 0.f};
#pragma unroll
  for (int m = 0; m < 2; m++)
#pragma unroll
    for (int n = 0; n < 2; n++) acc[m][n] = zero4;

  const int tsrow = w * 4 + (l >> 4);          // row within 32-row inst chunk
  const int tschk = (l & 15) ^ (tsrow & 15);   // pre-swizzled source 16B chunk
  const size_t tarow0 = (size_t)qr * 64;
  const size_t tbrow0 = (size_t)cbt * 256 + (size_t)qc * 128;

  const int q4 = (l >> 4) & 3;
  const int tarow_r = wr * 32 + (l & 15);
  const int tbrow_r = wc * 32 + (l & 15);

  TSG_A(0, 0, tA0); TSG_A(1, 0, tA0);
  TSG_B(0, 0, tB0); TSG_B(1, 0, tB0); TSG_B(2, 0, tB0); TSG_B(3, 0, tB0);
  TSG_A(0, 1, tA1); TSG_A(1, 1, tA1);
  TSG_B(0, 1, tB1); TSG_B(1, 1, tB1); TSG_B(2, 1, tB1); TSG_B(3, 1, tB1);
  WAITV(6);
  BARRIER();

  bf16x8 af[2][4], bf[2][4];
#pragma unroll
  for (int kk = 0; kk < 2; kk++) {
#pragma unroll
    for (int m2 = 0; m2 < 2; m2++) af[m2][kk] = TRD((const char*)tA0, tarow_r + m2 * 16, kk);
#pragma unroll
    for (int n = 0; n < 2; n++) bf[n][kk] = TRD((const char*)tB0, tbrow_r + n * 16, kk);
  }

#pragma unroll 1
  for (int tv = 0; tv < 6; ++tv) TTILE(tv, 1, 1, 1, 6)
  TTILE(6, 0, 1, 1, 0)
  TTILE(7, 0, 0, 0, 0)

  float rsum[2][4];
  float csum[2];
#pragma unroll
  for (int m = 0; m < 2; m++)
#pragma unroll
    for (int j = 0; j < 4; j++) rsum[m][j] = 0.f;
  csum[0] = 0.f; csum[1] = 0.f;

#pragma unroll
  for (int m = 0; m < 2; m++)
#pragma unroll
    for (int n = 0; n < 2; n++)
#pragma unroll
      for (int j = 0; j < 4; j++) {
        const float e = exp2f(acc[m][n][j] * EXPSCALE);
        rsum[m][j] += e;
        csum[n] += e;
      }
#pragma unroll
  for (int m = 0; m < 2; m++)
#pragma unroll
    for (int j = 0; j < 4; j++) {
      float v = rsum[m][j];
      v += __shfl_xor(v, 1); v += __shfl_xor(v, 2);
      v += __shfl_xor(v, 4); v += __shfl_xor(v, 8);
      rsum[m][j] = v;
    }
#pragma unroll
  for (int n = 0; n < 2; n++) {
    float v = csum[n];
    v += __shfl_xor(v, 16); v += __shfl_xor(v, 32);
    csum[n] = v;
  }

  const int col16 = l & 15, rgp = (l >> 4) & 3;
  float* rS = (float*)smem;            // [4 wc][64 rows]
  float* cS = ((float*)smem) + 256;    // [2 wr][128 cols]
  if (col16 == 0) {
#pragma unroll
    for (int m = 0; m < 2; m++)
#pragma unroll
      for (int j = 0; j < 4; j++)
        rS[wc * 64 + wr * 32 + m * 16 + rgp * 4 + j] = rsum[m][j];
  }
  if (rgp == 0) {
#pragma unroll
    for (int n = 0; n < 2; n++)
      cS[wr * 128 + wc * 32 + n * 16 + col16] = csum[n];
  }
  __syncthreads();
  if (t < 64) {
    const float rs = rS[t] + rS[64 + t] + rS[128 + t] + rS[192 + t];
    partial[(size_t)(cbt * 2 + qc) * N2 + qr * 64 + t] = rs;
  }
  if (t < 128) {
    const float cs = cS[t] + cS[128 + t];
    partial[(size_t)(64 + qr) * N2 + cbt * 256 + qc * 128 + t] = cs;
  }
}

// ---------------- Kernel C1: per-row denom; log; block sum --------------------------------
__device__ inline float blockReduce(float v, float* sred) {
#pragma unroll
  for (int o = 32; o > 0; o >>= 1) v += __shfl_xor(v, o);
  const int lane = threadIdx.x & 63, wid = threadIdx.x >> 6;
  if (lane == 0) sred[wid] = v;
  __syncthreads();
  v = sred[0] + sred[1] + sred[2] + sred[3];
  __syncthreads();
  return v;
}

__global__ __launch_bounds__(256) void kred1(const float* __restrict__ partial,
                                             float* __restrict__ bsum) {
  const int r = blockIdx.x * 256 + threadIdx.x;
  float d = 0.f;
#pragma unroll 8
  for (int cbx = 0; cbx < 64; ++cbx) d += partial[(size_t)cbx * N2 + r];
  if (blockIdx.x >= 16) {   // rows >= 4096: add tail colsum slots 64..67
#pragma unroll
    for (int cbx = 64; cbx < 68; ++cbx) d += partial[(size_t)cbx * N2 + r];
  }
  float v = logf(d);
  __shared__ float sred[4];
  v = blockReduce(v, sred);
  if (threadIdx.x == 0) bsum[blockIdx.x] = v;
}

// ---------------- Kernel C2: final scalar -------------------------------------------------
__global__ __launch_bounds__(256) void kred2(const float* __restrict__ bsum,
                                             const float* __restrict__ pos,
                                             float* __restrict__ out) {
  const int t = threadIdx.x;
  float v = (t < 32) ? bsum[t] : 0.f;
  float p = 0.f;
  for (int k = t; k < BSZ; k += 256) p += pos[k];
  __shared__ float sred[4];
  v = blockReduce(v, sred);
  p = blockReduce(p, sred);
  if (t == 0) out[0] = (v - 2.0f * p / TEMPV) / (float)N2;
}

extern "C" void kernel_launch(void* const* d_in, const int* in_sizes, int n_in,
                              void* d_out, int out_size, void* d_ws, size_t ws_size,
                              hipStream_t stream) {
  const float* ei = (const float*)d_in[0];
  const float* ej = (const float*)d_in[1];
  char* ws = (char*)d_ws;
  unsigned short* reps = (unsigned short*)ws;                          // 16 MB bf16 [8192][1024]
  unsigned char* reps8 = (unsigned char*)(ws + (size_t)16 * 1024 * 1024); // 8 MB fp8 (k-permuted)
  float* partial = (float*)(ws + (size_t)24 * 1024 * 1024);            // 2.13 MB [68][8192]
  float* pos = (float*)(ws + (size_t)24 * 1024 * 1024 + 2304 * 1024);  // 16 KB [4096]
  float* bsum = (float*)(ws + (size_t)24 * 1024 * 1024 + 2304 * 1024 + 16384); // 128 B

  (void)hipFuncSetAttribute((const void*)kgemm3,
                            hipFuncAttributeMaxDynamicSharedMemorySize, 65536);
  (void)hipFuncSetAttribute((const void*)kgemmt,
                            hipFuncAttributeMaxDynamicSharedMemorySize, 98304);

  knorm<<<BSZ, 256, 0, stream>>>(ei, ej, reps, reps8, pos);
  kgemm3<<<512, 512, 65536, stream>>>(reps8, partial);
  kgemmt<<<128, 512, 98304, stream>>>((const short*)reps, partial);
  kred1<<<32, 256, 0, stream>>>(partial, bsum);
  kred2<<<1, 256, 0, stream>>>(bsum, pos, (float*)d_out);
}

// Round 11
// 86.903 us; speedup vs baseline: 1.5944x; 1.0066x over previous
//
#include <hip/hip_runtime.h>

#define BSZ 4096
#define D 1024
#define N2 8192
#define TEMPV 0.5f
// exp(x/T) = exp2(x * log2(e)/T)
#define EXPSCALE 2.8853900817779268f
#define NTB 32      // 8192 / 256 tiles per dim

typedef __attribute__((ext_vector_type(8))) short bf16x8;
typedef __attribute__((ext_vector_type(4))) float f32x4;
typedef __attribute__((ext_vector_type(4))) int i32x4;
typedef __attribute__((ext_vector_type(8))) int i32x8;

__device__ inline unsigned short f2bf(float x) {
  unsigned int u = __float_as_uint(x);
  u += 0x7fffu + ((u >> 16) & 1u);   // round-to-nearest-even
  return (unsigned short)(u >> 16);
}

// bit-exact float -> OCP e4m3fn, RNE (inputs |x|<=1 here; clamp kept for safety)
__device__ inline unsigned int f2e4m3(float x) {
  unsigned int u = __float_as_uint(x);
  const unsigned int s = (u >> 24) & 0x80u;
  u &= 0x7fffffffu;
  const float a = __uint_as_float(u);
  if (a >= 448.0f) return s | 0x7Eu;
  if (a < 0.015625f) {                       // < 2^-6: subnormal
    const int m = (int)rintf(a * 512.0f);    // RNE; 8 -> 0x08 == 2^-6 exactly
    return s | (unsigned int)m;
  }
  u += 0x7FFFFu + ((u >> 20) & 1u);          // RNE to 3 mantissa bits
  const unsigned int e = u >> 23;            // biased f32 exp (>=121)
  const unsigned int m3 = (u >> 20) & 7u;
  return s | (((e - 120u) << 3) | m3);       // e4m3 bias 7
}

__device__ inline void gload16(const void* g, void* l) {
  __builtin_amdgcn_global_load_lds(
      (const __attribute__((address_space(1))) void*)g,
      (__attribute__((address_space(3))) void*)l, 16, 0, 0);
}

// ---------------- Kernel A: L2-normalize rows, emit bf16 + plain fp8 reps --------------
__global__ __launch_bounds__(256) void knorm(const float* __restrict__ ei,
                                             const float* __restrict__ ej,
                                             unsigned short* __restrict__ reps,
                                             unsigned char* __restrict__ reps8,
                                             float* __restrict__ pos) {
  const int r = blockIdx.x;
  const int t = threadIdx.x;
  const float4 vi = ((const float4*)(ei + (size_t)r * D))[t];
  const float4 vj = ((const float4*)(ej + (size_t)r * D))[t];
  float ssi = vi.x * vi.x + vi.y * vi.y + vi.z * vi.z + vi.w * vi.w;
  float ssj = vj.x * vj.x + vj.y * vj.y + vj.z * vj.z + vj.w * vj.w;
  float sij = vi.x * vj.x + vi.y * vj.y + vi.z * vj.z + vi.w * vj.w;
#pragma unroll
  for (int o = 32; o > 0; o >>= 1) {
    ssi += __shfl_xor(ssi, o);
    ssj += __shfl_xor(ssj, o);
    sij += __shfl_xor(sij, o);
  }
  __shared__ float red[12];
  const int lane = t & 63, wid = t >> 6;
  if (lane == 0) { red[wid * 3] = ssi; red[wid * 3 + 1] = ssj; red[wid * 3 + 2] = sij; }
  __syncthreads();
  ssi = red[0] + red[3] + red[6] + red[9];
  ssj = red[1] + red[4] + red[7] + red[10];
  sij = red[2] + red[5] + red[8] + red[11];
  const float inv_i = rsqrtf(fmaxf(ssi, 1e-24f));
  const float inv_j = rsqrtf(fmaxf(ssj, 1e-24f));
  const float xi0 = vi.x * inv_i, xi1 = vi.y * inv_i, xi2 = vi.z * inv_i, xi3 = vi.w * inv_i;
  const float xj0 = vj.x * inv_j, xj1 = vj.y * inv_j, xj2 = vj.z * inv_j, xj3 = vj.w * inv_j;
  ushort4 ui, uj;
  ui.x = f2bf(xi0); ui.y = f2bf(xi1); ui.z = f2bf(xi2); ui.w = f2bf(xi3);
  uj.x = f2bf(xj0); uj.y = f2bf(xj1); uj.z = f2bf(xj2); uj.w = f2bf(xj3);
  *((ushort4*)(reps + (size_t)r * D) + t) = ui;
  *((ushort4*)(reps + (size_t)(BSZ + r) * D) + t) = uj;
  const unsigned int pi = f2e4m3(xi0) | (f2e4m3(xi1) << 8) | (f2e4m3(xi2) << 16) | (f2e4m3(xi3) << 24);
  const unsigned int pj = f2e4m3(xj0) | (f2e4m3(xj1) << 8) | (f2e4m3(xj2) << 16) | (f2e4m3(xj3) << 24);
  *(unsigned int*)(reps8 + (size_t)r * 1024 + t * 4) = pi;
  *(unsigned int*)(reps8 + (size_t)(BSZ + r) * 1024 + t * 4) = pj;
  if (t == 0) pos[r] = sij * inv_i * inv_j;
}

// ======================= shared asm helpers =======================
#define BARRIER() do { __builtin_amdgcn_s_barrier(); asm volatile("" ::: "memory"); } while (0)
#define STR2(x) #x
#define WAITV(n) asm volatile("s_waitcnt vmcnt(" STR2(n) ")" ::: "memory")
#define LGKM0() asm volatile("s_waitcnt lgkmcnt(0)" ::: "memory")

// ---------------- Kernel B: 256x256 tiles, MX-scaled fp8 (unit scales), BK=128 ----------
// 8 waves (2M x 4N), wave tile 128x64. LDS 128 KiB: A dbuf 2x32KB + B dbuf 2x32KB,
// rows = 128B fp8, chunk XOR swizzle LDS[row][c] = orig[row][c ^ (row&7)].
// MFMA: mfma_scale_f32_16x16x128_f8f6f4, FMT=0 (e4m3), scales 0x7F7F7F7F (=1.0).
// Lane operand = 32 contiguous k-bytes (chunks 2q, 2q+1) -> two b128 LDS reads,
// conflict-free per quarter-wave (8 positions x 2 lanes/bank).
// Ledger/tile (4 A gloads @ph1 for t+1, 4 B gloads @ph3 for t+2): WAITV(4) at ph3
// retires A(t+1)+B(t+1) before ph4 reads them. Tile 6: WAITV(0). Prologue: WAITV(4).
#define SG_A(ii, ktv, dst) gload16(reps8 + (size_t)(arow0 + (ii) * 64 + (t >> 3)) * 1024 + \
                                       (ktv) * 128 + (((t & 7) ^ ((t >> 3) & 7)) << 4),    \
                                   (dst) + (size_t)(ii) * 8192 + (size_t)t * 16)
#define SG_B(ii, ktv, dst) gload16(reps8 + (size_t)(brow0 + (ii) * 64 + (t >> 3)) * 1024 + \
                                       (ktv) * 128 + (((t & 7) ^ ((t >> 3) & 7)) << 4),    \
                                   (dst) + (size_t)(ii) * 8192 + (size_t)t * 16)

#define READ_A2(buf, p) do {                                            \
    _Pragma("unroll") for (int m2_ = 0; m2_ < 2; m2_++) {               \
      const char* rp_ = (buf) + (size_t)(arow + ((p) * 2 + m2_) * 16) * 128; \
      i32x4 lo_ = *(const i32x4*)(rp_ + off0);                          \
      i32x4 hi_ = *(const i32x4*)(rp_ + off1);                          \
      afp[m2_] = __builtin_shufflevector(lo_, hi_, 0, 1, 2, 3, 4, 5, 6, 7); \
    }                                                                   \
  } while (0)

#define READ_B2(buf, n) do {                                            \
    const char* rp_ = (buf) + (size_t)(brow + (n) * 16) * 128;          \
    i32x4 lo_ = *(const i32x4*)(rp_ + off0);                            \
    i32x4 hi_ = *(const i32x4*)(rp_ + off1);                            \
    bfp[n] = __builtin_shufflevector(lo_, hi_, 0, 1, 2, 3, 4, 5, 6, 7); \
  } while (0)

// 8 scaled MFMA (K=128 each); bfp[0..1] half first so ph1's fresh bfp[2..3] have cover.
#define MFMA_P(p)                                                       \
  __builtin_amdgcn_s_setprio(1);                                        \
  _Pragma("unroll") for (int nh = 0; nh < 2; nh++)                      \
  _Pragma("unroll") for (int m2 = 0; m2 < 2; m2++)                      \
  _Pragma("unroll") for (int nn = 0; nn < 2; nn++) {                    \
    const int n_ = nh * 2 + nn;                                         \
    acc[2 * (p) + m2][n_] = __builtin_amdgcn_mfma_scale_f32_16x16x128_f8f6f4( \
        afp[m2], bfp[n_], acc[2 * (p) + m2][n_],                        \
        0, 0, 0, 0x7F7F7F7F, 0, 0x7F7F7F7F);                            \
  }                                                                     \
  __builtin_amdgcn_s_setprio(0);

#define DO_TILE(ktv, SA, SB, RDN, HASW, WV)                             \
  {                                                                     \
    const int cur = (ktv) & 1;                                          \
    const char* bA  = cur ? lA1 : lA0;                                  \
    const char* bB  = cur ? lB1 : lB0;                                  \
    const char* bAn = cur ? lA0 : lA1;                                  \
    const char* bBn = cur ? lB0 : lB1;                                  \
    char* stA = (char*)(cur ? lA0 : lA1);                               \
    char* stB = (char*)(cur ? lB1 : lB0);                               \
    /* ph1: P0 MFMA (ops from prev ph4); read bfp[2..3](t) + A frags 2,3; stage A(t+1) */ \
    READ_B2(bB, 2); READ_B2(bB, 3);                                     \
    MFMA_P(0);                                                          \
    READ_A2(bA, 1);                                                     \
    if (SA) { SG_A(0, (ktv) + 1, stA); SG_A(1, (ktv) + 1, stA);         \
              SG_A(2, (ktv) + 1, stA); SG_A(3, (ktv) + 1, stA); }       \
    BARRIER();                                                          \
    /* ph2 */                                                           \
    MFMA_P(1);                                                          \
    READ_A2(bA, 2);                                                     \
    BARRIER();                                                          \
    /* ph3: stage B(t+2); counted wait */                               \
    MFMA_P(2);                                                          \
    READ_A2(bA, 3);                                                     \
    if (SB) { SG_B(0, (ktv) + 2, stB); SG_B(1, (ktv) + 2, stB);         \
              SG_B(2, (ktv) + 2, stB); SG_B(3, (ktv) + 2, stB); }       \
    if (HASW) { WAITV(WV); }                                            \
    BARRIER();                                                          \
    /* ph4: read next tile's A frags 0,1 + bfp[0..1] */                 \
    MFMA_P(3);                                                          \
    if (RDN) { READ_A2(bAn, 0); READ_B2(bBn, 0); READ_B2(bBn, 1); }     \
    BARRIER();                                                          \
  }

__global__ __launch_bounds__(512, 2) void kgemm3(const unsigned char* __restrict__ reps8,
                                                 float* __restrict__ partial) {
  extern __shared__ char smem[];
  char* lA0 = smem;                           // 32 KB  [256 rows][128 B]
  char* lA1 = smem + 32768;
  char* lB0 = smem + 65536;
  char* lB1 = smem + 98304;

  // XCD-aware swizzle (512 = 8 * 64, bijective), then decode into the
  // 512-tile list: triangle minus tiles (0, 16..31).
  int bid = (int)blockIdx.x;
  bid = (bid & 7) * 64 + (bid >> 3);
  int rb, cb;
  if (bid < 16) {
    rb = 0; cb = bid;
  } else {
    int rem = bid - 16;
    rb = 1;
    while (rem >= NTB - rb) { rem -= NTB - rb; rb++; }
    cb = rb + rem;
  }

  const int t = threadIdx.x;
  const int l = t & 63, w = t >> 6;
  const int wr = w >> 2, wc = w & 3;          // 2 x 4 wave grid

  f32x4 acc[8][4];
  const f32x4 zero4 = {0.f, 0.f, 0.f, 0.f};
#pragma unroll
  for (int m = 0; m < 8; m++)
#pragma unroll
    for (int n = 0; n < 4; n++) acc[m][n] = zero4;

  const size_t arow0 = (size_t)rb * 256;
  const size_t brow0 = (size_t)cb * 256;

  // read-side: lane q-group holds orig chunks {2q, 2q+1}; LDS pos = chunk ^ (row&7)
  const int q2 = (l >> 4) & 3;
  const int arow = wr * 128 + (l & 15);
  const int brow = wc * 64 + (l & 15);
  const int r7 = l & 7;                       // == arow&7 == brow&7
  const int off0 = ((2 * q2) ^ r7) << 4;
  const int off1 = ((2 * q2 + 1) ^ r7) << 4;

  // ---- prologue: B(0), A(0), B(1); retire B(0)+A(0); preload tile-0 ph1 ops ----
  SG_B(0, 0, lB0); SG_B(1, 0, lB0); SG_B(2, 0, lB0); SG_B(3, 0, lB0);
  SG_A(0, 0, lA0); SG_A(1, 0, lA0); SG_A(2, 0, lA0); SG_A(3, 0, lA0);
  SG_B(0, 1, lB1); SG_B(1, 1, lB1); SG_B(2, 1, lB1); SG_B(3, 1, lB1);
  WAITV(4);
  BARRIER();

  i32x8 afp[2], bfp[4];
  READ_A2(lA0, 0);
  READ_B2(lB0, 0);
  READ_B2(lB0, 1);

#pragma unroll 1
  for (int kt = 0; kt < 6; ++kt) DO_TILE(kt, 1, 1, 1, 1, 4)
  DO_TILE(6, 1, 0, 1, 1, 0)
  DO_TILE(7, 0, 0, 0, 0, 0)

  // -------- epilogue: exp + diagonal mask + row/col partial sums --------
  float rsum[8][4];
  float csum[4];
#pragma unroll
  for (int m = 0; m < 8; m++)
#pragma unroll
    for (int j = 0; j < 4; j++) rsum[m][j] = 0.f;
#pragma unroll
  for (int n = 0; n < 4; n++) csum[n] = 0.f;

  const int col16 = l & 15, rgp = (l >> 4) & 3;
  const bool diag = (rb == cb);
  const int growbase = wr * 128 + rgp * 4;
  const int gcolbase = wc * 64 + col16;
#pragma unroll
  for (int m = 0; m < 8; m++) {
#pragma unroll
    for (int n = 0; n < 4; n++) {
#pragma unroll
      for (int j = 0; j < 4; j++) {
        const float e = (diag && (growbase + m * 16 + j) == (gcolbase + n * 16))
                            ? 0.f
                            : exp2f(acc[m][n][j] * EXPSCALE);
        rsum[m][j] += e;
        csum[n] += e;
      }
    }
  }
#pragma unroll
  for (int m = 0; m < 8; m++)
#pragma unroll
    for (int j = 0; j < 4; j++) {
      float v = rsum[m][j];
      v += __shfl_xor(v, 1); v += __shfl_xor(v, 2);
      v += __shfl_xor(v, 4); v += __shfl_xor(v, 8);
      rsum[m][j] = v;
    }
#pragma unroll
  for (int n = 0; n < 4; n++) {
    float v = csum[n];
    v += __shfl_xor(v, 16); v += __shfl_xor(v, 32);
    csum[n] = v;
  }

  float* rS = (float*)smem;            // [4 wc][256 rows]
  float* cS = ((float*)smem) + 1024;   // [2 wr][256 cols]
  if (col16 == 0) {
#pragma unroll
    for (int m = 0; m < 8; m++)
#pragma unroll
      for (int j = 0; j < 4; j++)
        rS[wc * 256 + wr * 128 + m * 16 + rgp * 4 + j] = rsum[m][j];
  }
  if (rgp == 0) {
#pragma unroll
    for (int n = 0; n < 4; n++)
      cS[wr * 256 + wc * 64 + n * 16 + col16] = csum[n];
  }
  __syncthreads();
  // partial layout: [68 col-blocks of 128][8192 rows]
  if (t < 256) {
    const float rs_lo = rS[t] + rS[256 + t];
    const float rs_hi = rS[512 + t] + rS[768 + t];
    partial[(size_t)(cb * 2) * N2 + rb * 256 + t] = rs_lo;
    partial[(size_t)(cb * 2 + 1) * N2 + rb * 256 + t] = rs_hi;
    if (!diag) {
      partial[(size_t)(rb * 2) * N2 + cb * 256 + t] = cS[t];
      partial[(size_t)(rb * 2 + 1) * N2 + cb * 256 + t] = cS[256 + t];
    }
  }
}

// ---------------- Kernel Bt: tail — 128 eighth-tiles (64x128) of tiles (0,16..31) -------
// bf16, unchanged (reads the bf16 reps copy).
#define TSG_A(ii, ktv, dst) gload16(reps + (tarow0 + (ii) * 32 + tsrow) * D + (ktv) * 128 + tschk * 8, \
                                    (dst) + (size_t)((ii) * 32 + w * 4) * 128)
#define TSG_B(ii, ktv, dst) gload16(reps + (tbrow0 + (ii) * 32 + tsrow) * D + (ktv) * 128 + tschk * 8, \
                                    (dst) + (size_t)((ii) * 32 + w * 4) * 128)

#define TRD(buf, row, kk) (*(const bf16x8*)((const char*)(buf) + (row) * 256 + \
                           ((((kk) * 4 + q4) ^ ((row) & 15)) << 4)))

#define TMFMA(kk)                                                       \
  __builtin_amdgcn_s_setprio(1);                                        \
  _Pragma("unroll") for (int m2 = 0; m2 < 2; m2++)                      \
  _Pragma("unroll") for (int n = 0; n < 2; n++)                         \
    acc[m2][n] = __builtin_amdgcn_mfma_f32_16x16x32_bf16(               \
        af[m2][kk], bf[n][kk], acc[m2][n], 0, 0, 0);                    \
  __builtin_amdgcn_s_setprio(0);

#define TTILE(tv, S, R, HASW, WV)                                       \
  {                                                                     \
    const int cur = (tv) & 1;                                           \
    const char* bA  = cur ? (const char*)tA1 : (const char*)tA0;        \
    const char* bB  = cur ? (const char*)tB1 : (const char*)tB0;        \
    const char* bAn = cur ? (const char*)tA0 : (const char*)tA1;        \
    const char* bBn = cur ? (const char*)tB0 : (const char*)tB1;        \
    short* stA = cur ? tA1 : tA0;   /* = bA buffer: parity(t+2) */      \
    short* stB = cur ? tB1 : tB0;                                       \
    _Pragma("unroll") for (int kk = 2; kk < 4; kk++) {                  \
      _Pragma("unroll") for (int m2 = 0; m2 < 2; m2++)                  \
        af[m2][kk] = TRD(bA, tarow_r + m2 * 16, kk);                    \
      _Pragma("unroll") for (int n = 0; n < 2; n++)                     \
        bf[n][kk] = TRD(bB, tbrow_r + n * 16, kk);                      \
    }                                                                   \
    TMFMA(0); TMFMA(1);                                                 \
    LGKM0();                                                            \
    BARRIER();                                                          \
    if (S) { TSG_A(0, (tv) + 2, stA); TSG_A(1, (tv) + 2, stA);          \
             TSG_B(0, (tv) + 2, stB); TSG_B(1, (tv) + 2, stB);          \
             TSG_B(2, (tv) + 2, stB); TSG_B(3, (tv) + 2, stB); }        \
    TMFMA(2); TMFMA(3);                                                 \
    if (HASW) { WAITV(WV); }                                            \
    BARRIER();                                                          \
    if (R) {                                                            \
      _Pragma("unroll") for (int kk = 0; kk < 2; kk++) {                \
        _Pragma("unroll") for (int m2 = 0; m2 < 2; m2++)                \
          af[m2][kk] = TRD(bAn, tarow_r + m2 * 16, kk);                 \
        _Pragma("unroll") for (int n = 0; n < 2; n++)                   \
          bf[n][kk] = TRD(bBn, tbrow_r + n * 16, kk);                   \
      }                                                                 \
    }                                                                   \
  }

__global__ __launch_bounds__(512) void kgemmt(const short* __restrict__ reps,
                                              float* __restrict__ partial) {
  extern __shared__ char smem[];
  short* tA0 = (short*)smem;                  // 16 KB [64][128]
  short* tA1 = (short*)(smem + 16384);
  short* tB0 = (short*)(smem + 32768);        // 32 KB [128][128]
  short* tB1 = (short*)(smem + 65536);

  const int b = (int)blockIdx.x;              // 0..127
  const int s = b >> 3, sub = b & 7;
  const int qr = sub >> 1;                    // 64-row chunk of rows 0..255
  const int qc = sub & 1;                     // 128-col half of the 256-col tile
  const int cbt = 16 + s;

  const int t = threadIdx.x;
  const int l = t & 63, w = t >> 6;
  const int wr = w >> 2, wc = w & 3;          // 2 x 4 wave grid

  f32x4 acc[2][2];
  const f32x4 zero4 = {0.f, 0.f, 0.f, 0.f};
#pragma unroll
  for (int m = 0; m < 2; m++)
#pragma unroll
    for (int n = 0; n < 2; n++) acc[m][n] = zero4;

  const int tsrow = w * 4 + (l >> 4);          // row within 32-row inst chunk
  const int tschk = (l & 15) ^ (tsrow & 15);   // pre-swizzled source 16B chunk
  const size_t tarow0 = (size_t)qr * 64;
  const size_t tbrow0 = (size_t)cbt * 256 + (size_t)qc * 128;

  const int q4 = (l >> 4) & 3;
  const int tarow_r = wr * 32 + (l & 15);
  const int tbrow_r = wc * 32 + (l & 15);

  TSG_A(0, 0, tA0); TSG_A(1, 0, tA0);
  TSG_B(0, 0, tB0); TSG_B(1, 0, tB0); TSG_B(2, 0, tB0); TSG_B(3, 0, tB0);
  TSG_A(0, 1, tA1); TSG_A(1, 1, tA1);
  TSG_B(0, 1, tB1); TSG_B(1, 1, tB1); TSG_B(2, 1, tB1); TSG_B(3, 1, tB1);
  WAITV(6);
  BARRIER();

  bf16x8 af[2][4], bf[2][4];
#pragma unroll
  for (int kk = 0; kk < 2; kk++) {
#pragma unroll
    for (int m2 = 0; m2 < 2; m2++) af[m2][kk] = TRD((const char*)tA0, tarow_r + m2 * 16, kk);
#pragma unroll
    for (int n = 0; n < 2; n++) bf[n][kk] = TRD((const char*)tB0, tbrow_r + n * 16, kk);
  }

#pragma unroll 1
  for (int tv = 0; tv < 6; ++tv) TTILE(tv, 1, 1, 1, 6)
  TTILE(6, 0, 1, 1, 0)
  TTILE(7, 0, 0, 0, 0)

  float rsum[2][4];
  float csum[2];
#pragma unroll
  for (int m = 0; m < 2; m++)
#pragma unroll
    for (int j = 0; j < 4; j++) rsum[m][j] = 0.f;
  csum[0] = 0.f; csum[1] = 0.f;

#pragma unroll
  for (int m = 0; m < 2; m++)
#pragma unroll
    for (int n = 0; n < 2; n++)
#pragma unroll
      for (int j = 0; j < 4; j++) {
        const float e = exp2f(acc[m][n][j] * EXPSCALE);
        rsum[m][j] += e;
        csum[n] += e;
      }
#pragma unroll
  for (int m = 0; m < 2; m++)
#pragma unroll
    for (int j = 0; j < 4; j++) {
      float v = rsum[m][j];
      v += __shfl_xor(v, 1); v += __shfl_xor(v, 2);
      v += __shfl_xor(v, 4); v += __shfl_xor(v, 8);
      rsum[m][j] = v;
    }
#pragma unroll
  for (int n = 0; n < 2; n++) {
    float v = csum[n];
    v += __shfl_xor(v, 16); v += __shfl_xor(v, 32);
    csum[n] = v;
  }

  const int col16 = l & 15, rgp = (l >> 4) & 3;
  float* rS = (float*)smem;            // [4 wc][64 rows]
  float* cS = ((float*)smem) + 256;    // [2 wr][128 cols]
  if (col16 == 0) {
#pragma unroll
    for (int m = 0; m < 2; m++)
#pragma unroll
      for (int j = 0; j < 4; j++)
        rS[wc * 64 + wr * 32 + m * 16 + rgp * 4 + j] = rsum[m][j];
  }
  if (rgp == 0) {
#pragma unroll
    for (int n = 0; n < 2; n++)
      cS[wr * 128 + wc * 32 + n * 16 + col16] = csum[n];
  }
  __syncthreads();
  if (t < 64) {
    const float rs = rS[t] + rS[64 + t] + rS[128 + t] + rS[192 + t];
    partial[(size_t)(cbt * 2 + qc) * N2 + qr * 64 + t] = rs;
  }
  if (t < 128) {
    const float cs = cS[t] + cS[128 + t];
    partial[(size_t)(64 + qr) * N2 + cbt * 256 + qc * 128 + t] = cs;
  }
}

// ---------------- Kernel C1: per-row denom; log; block sum --------------------------------
__device__ inline float blockReduce(float v, float* sred) {
#pragma unroll
  for (int o = 32; o > 0; o >>= 1) v += __shfl_xor(v, o);
  const int lane = threadIdx.x & 63, wid = threadIdx.x >> 6;
  if (lane == 0) sred[wid] = v;
  __syncthreads();
  v = sred[0] + sred[1] + sred[2] + sred[3];
  __syncthreads();
  return v;
}

__global__ __launch_bounds__(256) void kred1(const float* __restrict__ partial,
                                             float* __restrict__ bsum) {
  const int r = blockIdx.x * 256 + threadIdx.x;
  float d = 0.f;
#pragma unroll 8
  for (int cbx = 0; cbx < 64; ++cbx) d += partial[(size_t)cbx * N2 + r];
  if (blockIdx.x >= 16) {   // rows >= 4096: add tail colsum slots 64..67
#pragma unroll
    for (int cbx = 64; cbx < 68; ++cbx) d += partial[(size_t)cbx * N2 + r];
  }
  float v = logf(d);
  __shared__ float sred[4];
  v = blockReduce(v, sred);
  if (threadIdx.x == 0) bsum[blockIdx.x] = v;
}

// ---------------- Kernel C2: final scalar -------------------------------------------------
__global__ __launch_bounds__(256) void kred2(const float* __restrict__ bsum,
                                             const float* __restrict__ pos,
                                             float* __restrict__ out) {
  const int t = threadIdx.x;
  float v = (t < 32) ? bsum[t] : 0.f;
  float p = 0.f;
  for (int k = t; k < BSZ; k += 256) p += pos[k];
  __shared__ float sred[4];
  v = blockReduce(v, sred);
  p = blockReduce(p, sred);
  if (t == 0) out[0] = (v - 2.0f * p / TEMPV) / (float)N2;
}

extern "C" void kernel_launch(void* const* d_in, const int* in_sizes, int n_in,
                              void* d_out, int out_size, void* d_ws, size_t ws_size,
                              hipStream_t stream) {
  const float* ei = (const float*)d_in[0];
  const float* ej = (const float*)d_in[1];
  char* ws = (char*)d_ws;
  unsigned short* reps = (unsigned short*)ws;                          // 16 MB bf16 [8192][1024]
  unsigned char* reps8 = (unsigned char*)(ws + (size_t)16 * 1024 * 1024); // 8 MB fp8 (plain)
  float* partial = (float*)(ws + (size_t)24 * 1024 * 1024);            // 2.13 MB [68][8192]
  float* pos = (float*)(ws + (size_t)24 * 1024 * 1024 + 2304 * 1024);  // 16 KB [4096]
  float* bsum = (float*)(ws + (size_t)24 * 1024 * 1024 + 2304 * 1024 + 16384); // 128 B

  (void)hipFuncSetAttribute((const void*)kgemm3,
                            hipFuncAttributeMaxDynamicSharedMemorySize, 131072);
  (void)hipFuncSetAttribute((const void*)kgemmt,
                            hipFuncAttributeMaxDynamicSharedMemorySize, 98304);

  knorm<<<BSZ, 256, 0, stream>>>(ei, ej, reps, reps8, pos);
  kgemm3<<<512, 512, 131072, stream>>>(reps8, partial);
  kgemmt<<<128, 512, 98304, stream>>>((const short*)reps, partial);
  kred1<<<32, 256, 0, stream>>>(partial, bsum);
  kred2<<<1, 256, 0, stream>>>(bsum, pos, (float*)d_out);
}